// Round 1
// baseline (1841.254 us; speedup 1.0000x reference)
//
#include <hip/hip_runtime.h>

#define B_ 2
#define C_ 256
#define H_ 192
#define W_ 192
#define HW_ (H_*W_)
#define CHW_ (C_*HW_)
#define SCALE 0.125f
#define WT 32

__device__ __forceinline__ float4 ld4(const float* p) {
  return *reinterpret_cast<const float4*>(p);
}

// ---- transpose weights [co][ci][k] -> [ci][k][co] so per-thread (co) loads coalesce
__global__ __launch_bounds__(256) void wtrans_kernel(
    const float* __restrict__ w15, const float* __restrict__ w51,
    const float* __restrict__ w11,
    float* __restrict__ w15t, float* __restrict__ w51t, float* __restrict__ w11t) {
  int i = blockIdx.x * 256 + threadIdx.x;
  if (i < C_ * C_ * 5) {
    int co = i / (C_ * 5);
    int r  = i - co * (C_ * 5);
    int ci = r / 5;
    int k  = r - ci * 5;
    w15t[(ci * 5 + k) * C_ + co] = w15[i];
    w51t[(ci * 5 + k) * C_ + co] = w51[i];
  }
  if (i < C_ * C_) {
    int co = i / C_;
    int ci = i - co * C_;
    w11t[ci * C_ + co] = w11[i];
  }
}

// ---- t1 = conv1x5(x) + b15   (pad_w = 2), NCHW out (scratch = d_out)
__global__ __launch_bounds__(256) void conv1x5_kernel(
    const float* __restrict__ x, const float* __restrict__ w15t,
    const float* __restrict__ b15, float* __restrict__ t1) {
  const int bh = blockIdx.x;
  const int b = bh / H_, h = bh - (bh / H_) * H_;
  const int w0 = blockIdx.y * WT;
  const int co = threadIdx.x;
  __shared__ float xs[WT + 4];
  float acc[WT];
#pragma unroll
  for (int j = 0; j < WT; ++j) acc[j] = 0.f;
  const float* xrow = x + (size_t)b * CHW_ + (size_t)h * W_;
  for (int ci = 0; ci < C_; ++ci) {
    __syncthreads();
    if (threadIdx.x < WT + 4) {
      int w = w0 - 2 + (int)threadIdx.x;
      xs[threadIdx.x] = (w >= 0 && w < W_) ? xrow[(size_t)ci * HW_ + w] : 0.f;
    }
    __syncthreads();
    const float* wp = w15t + (size_t)ci * 5 * C_ + co;
    float g0 = wp[0], g1 = wp[C_], g2 = wp[2 * C_], g3 = wp[3 * C_], g4 = wp[4 * C_];
#pragma unroll
    for (int j = 0; j < WT; ++j)
      acc[j] += g0 * xs[j] + g1 * xs[j + 1] + g2 * xs[j + 2] + g3 * xs[j + 3] + g4 * xs[j + 4];
  }
  float bias = b15[co];
  float* tp = t1 + ((size_t)(b * C_ + co)) * HW_ + (size_t)h * W_ + w0;
#pragma unroll
  for (int j = 0; j < WT; ++j) tp[j] = acc[j] + bias;
}

// ---- feat = conv5x1(t1) + b51 + conv1x1(x) + b11  (pad_h = 2), written NHWC
__global__ __launch_bounds__(256) void conv5x1_kernel(
    const float* __restrict__ t1, const float* __restrict__ x,
    const float* __restrict__ w51t, const float* __restrict__ w11t,
    const float* __restrict__ b51, const float* __restrict__ b11,
    float* __restrict__ featT) {
  const int bh = blockIdx.x;
  const int b = bh / H_, h = bh - (bh / H_) * H_;
  const int w0 = blockIdx.y * WT;
  const int co = threadIdx.x;
  float acc[WT];
#pragma unroll
  for (int j = 0; j < WT; ++j) acc[j] = 0.f;
  int hh[5];
  float m[5];
#pragma unroll
  for (int k = 0; k < 5; ++k) {
    int t = h - 2 + k;
    m[k] = (t >= 0 && t < H_) ? 1.f : 0.f;  // fold zero-padding into the weight
    hh[k] = t < 0 ? 0 : (t >= H_ ? H_ - 1 : t);
  }
  const float* t1b = t1 + (size_t)b * CHW_ + w0;
  const float* xb  = x  + (size_t)b * CHW_ + (size_t)h * W_ + w0;
  for (int ci = 0; ci < C_; ++ci) {
    const float* wp = w51t + (size_t)ci * 5 * C_ + co;
    float g0 = wp[0] * m[0], g1 = wp[C_] * m[1], g2 = wp[2 * C_] * m[2],
          g3 = wp[3 * C_] * m[3], g4 = wp[4 * C_] * m[4];
    float gx = w11t[(size_t)ci * C_ + co];
    const float* p  = t1b + (size_t)ci * HW_;
    const float* px = xb  + (size_t)ci * HW_;
#pragma unroll
    for (int jq = 0; jq < WT / 4; ++jq) {
      float4 a0 = ld4(p + (size_t)hh[0] * W_ + jq * 4);
      float4 a1 = ld4(p + (size_t)hh[1] * W_ + jq * 4);
      float4 a2 = ld4(p + (size_t)hh[2] * W_ + jq * 4);
      float4 a3 = ld4(p + (size_t)hh[3] * W_ + jq * 4);
      float4 a4 = ld4(p + (size_t)hh[4] * W_ + jq * 4);
      float4 ax = ld4(px + jq * 4);
      acc[jq * 4 + 0] += g0 * a0.x + g1 * a1.x + g2 * a2.x + g3 * a3.x + g4 * a4.x + gx * ax.x;
      acc[jq * 4 + 1] += g0 * a0.y + g1 * a1.y + g2 * a2.y + g3 * a3.y + g4 * a4.y + gx * ax.y;
      acc[jq * 4 + 2] += g0 * a0.z + g1 * a1.z + g2 * a2.z + g3 * a3.z + g4 * a4.z + gx * ax.z;
      acc[jq * 4 + 3] += g0 * a0.w + g1 * a1.w + g2 * a2.w + g3 * a3.w + g4 * a4.w + gx * ax.w;
    }
  }
  float bias = b51[co] + b11[co];
  float* fp = featT + ((size_t)((b * H_ + h) * W_ + w0)) * C_ + co;
#pragma unroll
  for (int j = 0; j < WT; ++j) fp[(size_t)j * C_] = acc[j] + bias;
}

// ---- out = x + feat + bilinear_gather(feat at box center)   (mmcv semantics)
__global__ __launch_bounds__(256) void align_kernel(
    const float* __restrict__ x, const float* __restrict__ featT,
    const float* __restrict__ boxes, float* __restrict__ out) {
  int p = blockIdx.x * 256 + threadIdx.x;  // 0 .. B*H*W-1
  int b = p / HW_;
  int p2 = p - b * HW_;
  float yy = boxes[(size_t)p * 5 + 0] * SCALE;
  float xx = boxes[(size_t)p * 5 + 1] * SCALE;
  bool valid = (yy >= -1.0f) && (yy <= (float)H_) && (xx >= -1.0f) && (xx <= (float)W_);
  yy = fmaxf(yy, 0.f);
  xx = fmaxf(xx, 0.f);
  int yl = (int)floorf(yy), xl = (int)floorf(xx);
  int yh, xh;
  if (yl >= H_ - 1) { yl = H_ - 1; yh = H_ - 1; yy = (float)(H_ - 1); } else { yh = yl + 1; }
  if (xl >= W_ - 1) { xl = W_ - 1; xh = W_ - 1; xx = (float)(W_ - 1); } else { xh = xl + 1; }
  float ly = yy - (float)yl, lx = xx - (float)xl;
  float hy = 1.f - ly, hx = 1.f - lx;
  float q00 = hy * hx, q01 = hy * lx, q10 = ly * hx, q11 = ly * lx;
  if (!valid) { q00 = 0.f; q01 = 0.f; q10 = 0.f; q11 = 0.f; }
  const float* fT  = featT + (size_t)b * (size_t)HW_ * C_;
  const float* f00 = fT + ((size_t)yl * W_ + xl) * C_;
  const float* f01 = fT + ((size_t)yl * W_ + xh) * C_;
  const float* f10 = fT + ((size_t)yh * W_ + xl) * C_;
  const float* f11 = fT + ((size_t)yh * W_ + xh) * C_;
  const float* fc  = fT + (size_t)p2 * C_;
  const float* xc  = x + (size_t)b * CHW_ + p2;
  float* oc = out + (size_t)b * CHW_ + p2;
#pragma unroll 4
  for (int c = 0; c < C_; c += 4) {
    float4 a = ld4(f00 + c), bb = ld4(f01 + c), cc = ld4(f10 + c), dd = ld4(f11 + c);
    float4 e = ld4(fc + c);
    float v0 = q00 * a.x + q01 * bb.x + q10 * cc.x + q11 * dd.x;
    float v1 = q00 * a.y + q01 * bb.y + q10 * cc.y + q11 * dd.y;
    float v2 = q00 * a.z + q01 * bb.z + q10 * cc.z + q11 * dd.z;
    float v3 = q00 * a.w + q01 * bb.w + q10 * cc.w + q11 * dd.w;
    oc[(size_t)(c + 0) * HW_] = xc[(size_t)(c + 0) * HW_] + e.x + v0;
    oc[(size_t)(c + 1) * HW_] = xc[(size_t)(c + 1) * HW_] + e.y + v1;
    oc[(size_t)(c + 2) * HW_] = xc[(size_t)(c + 2) * HW_] + e.z + v2;
    oc[(size_t)(c + 3) * HW_] = xc[(size_t)(c + 3) * HW_] + e.w + v3;
  }
}

extern "C" void kernel_launch(void* const* d_in, const int* in_sizes, int n_in,
                              void* d_out, int out_size, void* d_ws, size_t ws_size,
                              hipStream_t stream) {
  const float* x     = (const float*)d_in[0];
  const float* boxes = (const float*)d_in[1];
  const float* w51   = (const float*)d_in[2];
  const float* b51   = (const float*)d_in[3];
  const float* w15   = (const float*)d_in[4];
  const float* b15   = (const float*)d_in[5];
  const float* w11   = (const float*)d_in[6];
  const float* b11   = (const float*)d_in[7];
  float* out = (float*)d_out;

  // workspace layout: feat (NHWC) | w15t | w51t | w11t   (~78.4 MB)
  float* featT = (float*)d_ws;
  float* w15t = featT + (size_t)B_ * HW_ * C_;
  float* w51t = w15t + C_ * C_ * 5;
  float* w11t = w51t + C_ * C_ * 5;
  float* t1 = out;  // reuse d_out as t1 scratch (fully rewritten by align later)

  wtrans_kernel<<<dim3((C_ * C_ * 5 + 255) / 256), 256, 0, stream>>>(
      w15, w51, w11, w15t, w51t, w11t);
  conv1x5_kernel<<<dim3(B_ * H_, W_ / WT), 256, 0, stream>>>(x, w15t, b15, t1);
  conv5x1_kernel<<<dim3(B_ * H_, W_ / WT), 256, 0, stream>>>(
      t1, x, w51t, w11t, b51, b11, featT);
  align_kernel<<<dim3(B_ * HW_ / 256), 256, 0, stream>>>(x, featT, boxes, out);
}

// Round 2
// 368.617 us; speedup vs baseline: 4.9950x; 4.9950x over previous
//
#include <hip/hip_runtime.h>
#include <hip/hip_bf16.h>
#include <stdint.h>

#define B_ 2
#define C_ 256
#define H_ 192
#define W_ 192
#define HW_ (H_*W_)
#define CHW_ (C_*HW_)
#define P_ (B_*HW_)
#define SCALE 0.125f

typedef __attribute__((ext_vector_type(8))) short bf16x8;
typedef __attribute__((ext_vector_type(4))) float f32x4;

__device__ __forceinline__ float4 ld4(const float* p) {
  return *reinterpret_cast<const float4*>(p);
}

__device__ __forceinline__ void gload_lds16(const void* g, void* l) {
  __builtin_amdgcn_global_load_lds(
      (const __attribute__((address_space(1))) uint32_t*)g,
      (__attribute__((address_space(3))) uint32_t*)l, 16, 0, 0);
}

// ---- weights: w15/w51 [co][ci][k] fp32 -> bf16 [co][k*256+ci]; w11 appended; zero zbuf
__global__ __launch_bounds__(256) void wtrans_kernel(
    const float* __restrict__ w15, const float* __restrict__ w51,
    const float* __restrict__ w11,
    __hip_bfloat16* __restrict__ w1t, __hip_bfloat16* __restrict__ w2t,
    __hip_bfloat16* __restrict__ zbuf) {
  int i = blockIdx.x * 256 + threadIdx.x;
  if (i < C_ * C_ * 5) {
    int co = i / (C_ * 5);
    int r  = i - co * (C_ * 5);
    int ci = r / 5;
    int k  = r - ci * 5;
    w1t[(size_t)co * 1280 + k * 256 + ci] = __float2bfloat16(w15[i]);
    w2t[(size_t)co * 1536 + k * 256 + ci] = __float2bfloat16(w51[i]);
  }
  if (i < C_ * C_) {
    int co = i >> 8, ci = i & 255;
    w2t[(size_t)co * 1536 + 1280 + ci] = __float2bfloat16(w11[i]);
  }
  if (i < 1024) zbuf[i] = __float2bfloat16(0.f);
}

// ---- x NCHW fp32 -> xT NHWC bf16 (LDS 32x32 tile transpose)
__global__ __launch_bounds__(256) void nchw2nhwc_kernel(
    const float* __restrict__ x, __hip_bfloat16* __restrict__ xT) {
  __shared__ float tile[32][33];
  int p0 = blockIdx.x * 32, c0 = blockIdx.y * 32, b = blockIdx.z;
  int tx = threadIdx.x, ty = threadIdx.y;
  const float* xb = x + (size_t)b * CHW_;
#pragma unroll
  for (int j = 0; j < 4; ++j)
    tile[ty + j * 8][tx] = xb[(size_t)(c0 + ty + j * 8) * HW_ + p0 + tx];
  __syncthreads();
  __hip_bfloat16* xo = xT + (size_t)b * HW_ * C_;
#pragma unroll
  for (int j = 0; j < 4; ++j)
    xo[(size_t)(p0 + ty + j * 8) * C_ + c0 + tx] = __float2bfloat16(tile[tx][ty + j * 8]);
}

// ---- GEMM1: t1[p][co] = bf16( sum_{k,ci} xT[p+(k-2)][ci] * w15[co][ci][k] + b15[co] )
// M=P_ pixels, N=256, K=1280 (K = k*256+ci). 128x128 tile, BK=64, 4 waves 2x2.
__global__ __launch_bounds__(256) void gemm1_kernel(
    const __hip_bfloat16* __restrict__ xT, const __hip_bfloat16* __restrict__ w1t,
    const float* __restrict__ b15, __hip_bfloat16* __restrict__ t1,
    const __hip_bfloat16* __restrict__ zbuf) {
  __shared__ __align__(16) char lds[32768];  // A: [0,16K)  B: [16K,32K)
  int bid = blockIdx.x;
  bid = (bid & 7) * (gridDim.x >> 3) + (bid >> 3);  // XCD swizzle (1152 % 8 == 0)
  const int nb = bid & 1, mb = bid >> 1;
  const int p0 = mb * 128;
  const int tid = threadIdx.x, l = tid & 63, wid = tid >> 6;
  const int wrow = (wid >> 1) * 64, wcol = (wid & 1) * 64;
  const int sboff = (((l & 7) ^ (l >> 3)) << 4);  // swizzled 16B-block byte offset (source side)

  // per-issue lane constants (rows r = is*8 + (l>>3); r&7 == l>>3)
  int pbase[4], wv[4], cobase[4];
#pragma unroll
  for (int ii = 0; ii < 4; ++ii) {
    int is = wid * 4 + ii;
    pbase[ii] = p0 + is * 8 + (l >> 3);
    wv[ii] = pbase[ii] % 192;
    cobase[ii] = nb * 128 + is * 8 + (l >> 3);
  }
  // ds_read addresses (constant across kb): row&7 == l&7
  int a_ad[4][2], b_ad[4][2];
#pragma unroll
  for (int m = 0; m < 4; ++m)
#pragma unroll
    for (int kk = 0; kk < 2; ++kk) {
      int blk = ((kk * 4 + (l >> 4)) ^ (l & 7)) << 4;
      a_ad[m][kk] = (wrow + m * 16 + (l & 15)) * 128 + blk;
      b_ad[m][kk] = 16384 + (wcol + m * 16 + (l & 15)) * 128 + blk;
    }

  f32x4 acc[4][4] = {};
  const char* xTb = (const char*)xT;
  const char* wB  = (const char*)w1t;
  const char* zb  = (const char*)zbuf;

  for (int kb = 0; kb < 20; ++kb) {
    int k = kb >> 2, dl = k - 2;
    int cib = (kb & 3) * 128;  // ci0 bytes
    __syncthreads();
#pragma unroll
    for (int ii = 0; ii < 4; ++ii) {
      int is = wid * 4 + ii;
      const char* src = ((unsigned)(wv[ii] + dl) < 192u)
          ? xTb + (size_t)(pbase[ii] + dl) * 512 + cib + sboff
          : zb + sboff;
      gload_lds16(src, lds + is * 1024);
      const char* bs = wB + (size_t)cobase[ii] * 2560 + kb * 128 + sboff;
      gload_lds16(bs, lds + 16384 + is * 1024);
    }
    __syncthreads();
#pragma unroll
    for (int kk = 0; kk < 2; ++kk) {
      bf16x8 af[4], bfr[4];
#pragma unroll
      for (int m = 0; m < 4; ++m) af[m] = *(const bf16x8*)(lds + a_ad[m][kk]);
#pragma unroll
      for (int n = 0; n < 4; ++n) bfr[n] = *(const bf16x8*)(lds + b_ad[n][kk]);
#pragma unroll
      for (int m = 0; m < 4; ++m)
#pragma unroll
        for (int n = 0; n < 4; ++n)
          acc[m][n] = __builtin_amdgcn_mfma_f32_16x16x32_bf16(af[m], bfr[n], acc[m][n], 0, 0, 0);
    }
  }
  // epilogue: C row = pixel, col = co  (col=lane&15, row=(lane>>4)*4+reg)
#pragma unroll
  for (int n = 0; n < 4; ++n) {
    int co = nb * 128 + wcol + n * 16 + (l & 15);
    float bias = b15[co];
#pragma unroll
    for (int m = 0; m < 4; ++m) {
      int prow = p0 + wrow + m * 16 + (l >> 4) * 4;
#pragma unroll
      for (int r = 0; r < 4; ++r)
        t1[(size_t)(prow + r) * 256 + co] = __float2bfloat16(acc[m][n][r] + bias);
    }
  }
}

// ---- GEMM2: feat[p][co] = sum_{k,ci} t1[p+(k-2)*W][ci]*w51 + sum_ci xT[p][ci]*w11 + b51+b11
// K = 1280 (t1) + 256 (xT) = 1536
__global__ __launch_bounds__(256) void gemm2_kernel(
    const __hip_bfloat16* __restrict__ t1, const __hip_bfloat16* __restrict__ xT,
    const __hip_bfloat16* __restrict__ w2t,
    const float* __restrict__ b51, const float* __restrict__ b11,
    float* __restrict__ featT, const __hip_bfloat16* __restrict__ zbuf) {
  __shared__ __align__(16) char lds[32768];
  int bid = blockIdx.x;
  bid = (bid & 7) * (gridDim.x >> 3) + (bid >> 3);
  const int nb = bid & 1, mb = bid >> 1;
  const int p0 = mb * 128;
  const int tid = threadIdx.x, l = tid & 63, wid = tid >> 6;
  const int wrow = (wid >> 1) * 64, wcol = (wid & 1) * 64;
  const int sboff = (((l & 7) ^ (l >> 3)) << 4);

  int pbase[4], hv[4], cobase[4];
#pragma unroll
  for (int ii = 0; ii < 4; ++ii) {
    int is = wid * 4 + ii;
    pbase[ii] = p0 + is * 8 + (l >> 3);
    hv[ii] = (pbase[ii] / 192) % 192;
    cobase[ii] = nb * 128 + is * 8 + (l >> 3);
  }
  int a_ad[4][2], b_ad[4][2];
#pragma unroll
  for (int m = 0; m < 4; ++m)
#pragma unroll
    for (int kk = 0; kk < 2; ++kk) {
      int blk = ((kk * 4 + (l >> 4)) ^ (l & 7)) << 4;
      a_ad[m][kk] = (wrow + m * 16 + (l & 15)) * 128 + blk;
      b_ad[m][kk] = 16384 + (wcol + m * 16 + (l & 15)) * 128 + blk;
    }

  f32x4 acc[4][4] = {};
  const char* t1b = (const char*)t1;
  const char* xTb = (const char*)xT;
  const char* wB  = (const char*)w2t;
  const char* zb  = (const char*)zbuf;

  for (int kb = 0; kb < 24; ++kb) {
    __syncthreads();
#pragma unroll
    for (int ii = 0; ii < 4; ++ii) {
      int is = wid * 4 + ii;
      const char* src;
      if (kb < 20) {
        int k = kb >> 2, dl = k - 2;
        src = ((unsigned)(hv[ii] + dl) < 192u)
            ? t1b + (size_t)(pbase[ii] + dl * 192) * 512 + (kb & 3) * 128 + sboff
            : zb + sboff;
      } else {
        src = xTb + (size_t)pbase[ii] * 512 + (kb - 20) * 128 + sboff;
      }
      gload_lds16(src, lds + is * 1024);
      const char* bs = wB + (size_t)cobase[ii] * 3072 + kb * 128 + sboff;
      gload_lds16(bs, lds + 16384 + is * 1024);
    }
    __syncthreads();
#pragma unroll
    for (int kk = 0; kk < 2; ++kk) {
      bf16x8 af[4], bfr[4];
#pragma unroll
      for (int m = 0; m < 4; ++m) af[m] = *(const bf16x8*)(lds + a_ad[m][kk]);
#pragma unroll
      for (int n = 0; n < 4; ++n) bfr[n] = *(const bf16x8*)(lds + b_ad[n][kk]);
#pragma unroll
      for (int m = 0; m < 4; ++m)
#pragma unroll
        for (int n = 0; n < 4; ++n)
          acc[m][n] = __builtin_amdgcn_mfma_f32_16x16x32_bf16(af[m], bfr[n], acc[m][n], 0, 0, 0);
    }
  }
#pragma unroll
  for (int n = 0; n < 4; ++n) {
    int co = nb * 128 + wcol + n * 16 + (l & 15);
    float bias = b51[co] + b11[co];
#pragma unroll
    for (int m = 0; m < 4; ++m) {
      int prow = p0 + wrow + m * 16 + (l >> 4) * 4;
#pragma unroll
      for (int r = 0; r < 4; ++r)
        featT[(size_t)(prow + r) * 256 + co] = acc[m][n][r] + bias;
    }
  }
}

// ---- out = x + feat + bilinear_gather(feat at box center)   (mmcv semantics)
__global__ __launch_bounds__(256) void align_kernel(
    const float* __restrict__ x, const float* __restrict__ featT,
    const float* __restrict__ boxes, float* __restrict__ out) {
  int p = blockIdx.x * 256 + threadIdx.x;  // 0 .. B*H*W-1
  int b = p / HW_;
  int p2 = p - b * HW_;
  float yy = boxes[(size_t)p * 5 + 0] * SCALE;
  float xx = boxes[(size_t)p * 5 + 1] * SCALE;
  bool valid = (yy >= -1.0f) && (yy <= (float)H_) && (xx >= -1.0f) && (xx <= (float)W_);
  yy = fmaxf(yy, 0.f);
  xx = fmaxf(xx, 0.f);
  int yl = (int)floorf(yy), xl = (int)floorf(xx);
  int yh, xh;
  if (yl >= H_ - 1) { yl = H_ - 1; yh = H_ - 1; yy = (float)(H_ - 1); } else { yh = yl + 1; }
  if (xl >= W_ - 1) { xl = W_ - 1; xh = W_ - 1; xx = (float)(W_ - 1); } else { xh = xl + 1; }
  float ly = yy - (float)yl, lx = xx - (float)xl;
  float hy = 1.f - ly, hx = 1.f - lx;
  float q00 = hy * hx, q01 = hy * lx, q10 = ly * hx, q11 = ly * lx;
  if (!valid) { q00 = 0.f; q01 = 0.f; q10 = 0.f; q11 = 0.f; }
  const float* fT  = featT + (size_t)b * (size_t)HW_ * C_;
  const float* f00 = fT + ((size_t)yl * W_ + xl) * C_;
  const float* f01 = fT + ((size_t)yl * W_ + xh) * C_;
  const float* f10 = fT + ((size_t)yh * W_ + xl) * C_;
  const float* f11 = fT + ((size_t)yh * W_ + xh) * C_;
  const float* fc  = fT + (size_t)p2 * C_;
  const float* xc  = x + (size_t)b * CHW_ + p2;
  float* oc = out + (size_t)b * CHW_ + p2;
#pragma unroll 4
  for (int c = 0; c < C_; c += 4) {
    float4 a = ld4(f00 + c), bb = ld4(f01 + c), cc = ld4(f10 + c), dd = ld4(f11 + c);
    float4 e = ld4(fc + c);
    float v0 = q00 * a.x + q01 * bb.x + q10 * cc.x + q11 * dd.x;
    float v1 = q00 * a.y + q01 * bb.y + q10 * cc.y + q11 * dd.y;
    float v2 = q00 * a.z + q01 * bb.z + q10 * cc.z + q11 * dd.z;
    float v3 = q00 * a.w + q01 * bb.w + q10 * cc.w + q11 * dd.w;
    oc[(size_t)(c + 0) * HW_] = xc[(size_t)(c + 0) * HW_] + e.x + v0;
    oc[(size_t)(c + 1) * HW_] = xc[(size_t)(c + 1) * HW_] + e.y + v1;
    oc[(size_t)(c + 2) * HW_] = xc[(size_t)(c + 2) * HW_] + e.z + v2;
    oc[(size_t)(c + 3) * HW_] = xc[(size_t)(c + 3) * HW_] + e.w + v3;
  }
}

extern "C" void kernel_launch(void* const* d_in, const int* in_sizes, int n_in,
                              void* d_out, int out_size, void* d_ws, size_t ws_size,
                              hipStream_t stream) {
  const float* x     = (const float*)d_in[0];
  const float* boxes = (const float*)d_in[1];
  const float* w51   = (const float*)d_in[2];
  const float* b51   = (const float*)d_in[3];
  const float* w15   = (const float*)d_in[4];
  const float* b15   = (const float*)d_in[5];
  const float* w11   = (const float*)d_in[6];
  const float* b11   = (const float*)d_in[7];
  float* out = (float*)d_out;

  // d_ws: featT fp32 NHWC | w1t bf16 | w2t bf16 | zbuf   (~77 MB)
  float* featT = (float*)d_ws;
  __hip_bfloat16* w1t  = (__hip_bfloat16*)(featT + (size_t)P_ * C_);
  __hip_bfloat16* w2t  = w1t + (size_t)C_ * 1280;
  __hip_bfloat16* zbuf = w2t + (size_t)C_ * 1536;
  // d_out doubles as scratch: t1 bf16 NHWC | xT bf16 NHWC (both dead before align writes out)
  __hip_bfloat16* t1 = (__hip_bfloat16*)d_out;
  __hip_bfloat16* xT = t1 + (size_t)P_ * C_;

  wtrans_kernel<<<dim3((C_ * C_ * 5 + 255) / 256), 256, 0, stream>>>(
      w15, w51, w11, w1t, w2t, zbuf);
  nchw2nhwc_kernel<<<dim3(HW_ / 32, C_ / 32, B_), dim3(32, 8), 0, stream>>>(x, xT);
  gemm1_kernel<<<dim3(P_ / 128 * 2), 256, 0, stream>>>(xT, w1t, b15, t1, zbuf);
  gemm2_kernel<<<dim3(P_ / 128 * 2), 256, 0, stream>>>(t1, xT, w2t, b51, b11, featT, zbuf);
  align_kernel<<<dim3(P_ / 256), 256, 0, stream>>>(x, featT, boxes, out);
}

// Round 3
// 334.054 us; speedup vs baseline: 5.5119x; 1.1035x over previous
//
#include <hip/hip_runtime.h>
#include <hip/hip_bf16.h>
#include <stdint.h>

#define B_ 2
#define C_ 256
#define H_ 192
#define W_ 192
#define HW_ (H_*W_)
#define CHW_ (C_*HW_)
#define P_ (B_*HW_)
#define SCALE 0.125f

typedef __attribute__((ext_vector_type(8))) short bf16x8;
typedef __attribute__((ext_vector_type(4))) float f32x4;

__device__ __forceinline__ float4 ld4(const float* p) {
  return *reinterpret_cast<const float4*>(p);
}

__device__ __forceinline__ void gload_lds16(const void* g, void* l) {
  __builtin_amdgcn_global_load_lds(
      (const __attribute__((address_space(1))) uint32_t*)g,
      (__attribute__((address_space(3))) uint32_t*)l, 16, 0, 0);
}

// ---- weights: w15/w51 [co][ci][k] fp32 -> bf16 [co][k*256+ci]; w11 appended; zero zbuf
__global__ __launch_bounds__(256) void wtrans_kernel(
    const float* __restrict__ w15, const float* __restrict__ w51,
    const float* __restrict__ w11,
    __hip_bfloat16* __restrict__ w1t, __hip_bfloat16* __restrict__ w2t,
    __hip_bfloat16* __restrict__ zbuf) {
  int i = blockIdx.x * 256 + threadIdx.x;
  if (i < C_ * C_ * 5) {
    int co = i / (C_ * 5);
    int r  = i - co * (C_ * 5);
    int ci = r / 5;
    int k  = r - ci * 5;
    w1t[(size_t)co * 1280 + k * 256 + ci] = __float2bfloat16(w15[i]);
    w2t[(size_t)co * 1536 + k * 256 + ci] = __float2bfloat16(w51[i]);
  }
  if (i < C_ * C_) {
    int co = i >> 8, ci = i & 255;
    w2t[(size_t)co * 1536 + 1280 + ci] = __float2bfloat16(w11[i]);
  }
  if (i < 1024) zbuf[i] = __float2bfloat16(0.f);
}

// ---- x NCHW fp32 -> xT NHWC bf16 (LDS 32x32 tile transpose)
__global__ __launch_bounds__(256) void nchw2nhwc_kernel(
    const float* __restrict__ x, __hip_bfloat16* __restrict__ xT) {
  __shared__ float tile[32][33];
  int p0 = blockIdx.x * 32, c0 = blockIdx.y * 32, b = blockIdx.z;
  int tx = threadIdx.x, ty = threadIdx.y;
  const float* xb = x + (size_t)b * CHW_;
#pragma unroll
  for (int j = 0; j < 4; ++j)
    tile[ty + j * 8][tx] = xb[(size_t)(c0 + ty + j * 8) * HW_ + p0 + tx];
  __syncthreads();
  __hip_bfloat16* xo = xT + (size_t)b * HW_ * C_;
#pragma unroll
  for (int j = 0; j < 4; ++j)
    xo[(size_t)(p0 + ty + j * 8) * C_ + c0 + tx] = __float2bfloat16(tile[tx][ty + j * 8]);
}

// ---- GEMM1: t1[p][co] = bf16( sum_{k,ci} xT[p+(k-2)][ci] * w15[co][ci][k] + b15[co] )
__global__ __launch_bounds__(256) void gemm1_kernel(
    const __hip_bfloat16* __restrict__ xT, const __hip_bfloat16* __restrict__ w1t,
    const float* __restrict__ b15, __hip_bfloat16* __restrict__ t1,
    const __hip_bfloat16* __restrict__ zbuf) {
  __shared__ __align__(16) char lds[32768];  // A: [0,16K)  B: [16K,32K)
  int bid = blockIdx.x;
  bid = (bid & 7) * (gridDim.x >> 3) + (bid >> 3);  // XCD swizzle (1152 % 8 == 0)
  const int nb = bid & 1, mb = bid >> 1;
  const int p0 = mb * 128;
  const int tid = threadIdx.x, l = tid & 63, wid = tid >> 6;
  const int wrow = (wid >> 1) * 64, wcol = (wid & 1) * 64;
  const int sboff = (((l & 7) ^ (l >> 3)) << 4);

  int pbase[4], wv[4], cobase[4];
#pragma unroll
  for (int ii = 0; ii < 4; ++ii) {
    int is = wid * 4 + ii;
    pbase[ii] = p0 + is * 8 + (l >> 3);
    wv[ii] = pbase[ii] % 192;
    cobase[ii] = nb * 128 + is * 8 + (l >> 3);
  }
  int a_ad[4][2], b_ad[4][2];
#pragma unroll
  for (int m = 0; m < 4; ++m)
#pragma unroll
    for (int kk = 0; kk < 2; ++kk) {
      int blk = ((kk * 4 + (l >> 4)) ^ (l & 7)) << 4;
      a_ad[m][kk] = (wrow + m * 16 + (l & 15)) * 128 + blk;
      b_ad[m][kk] = 16384 + (wcol + m * 16 + (l & 15)) * 128 + blk;
    }

  f32x4 acc[4][4] = {};
  const char* xTb = (const char*)xT;
  const char* wB  = (const char*)w1t;
  const char* zb  = (const char*)zbuf;

  for (int kb = 0; kb < 20; ++kb) {
    int k = kb >> 2, dl = k - 2;
    int cib = (kb & 3) * 128;
    __syncthreads();
#pragma unroll
    for (int ii = 0; ii < 4; ++ii) {
      int is = wid * 4 + ii;
      const char* src = ((unsigned)(wv[ii] + dl) < 192u)
          ? xTb + (size_t)(pbase[ii] + dl) * 512 + cib + sboff
          : zb + sboff;
      gload_lds16(src, lds + is * 1024);
      const char* bs = wB + (size_t)cobase[ii] * 2560 + kb * 128 + sboff;
      gload_lds16(bs, lds + 16384 + is * 1024);
    }
    __syncthreads();
#pragma unroll
    for (int kk = 0; kk < 2; ++kk) {
      bf16x8 af[4], bfr[4];
#pragma unroll
      for (int m = 0; m < 4; ++m) af[m] = *(const bf16x8*)(lds + a_ad[m][kk]);
#pragma unroll
      for (int n = 0; n < 4; ++n) bfr[n] = *(const bf16x8*)(lds + b_ad[n][kk]);
#pragma unroll
      for (int m = 0; m < 4; ++m)
#pragma unroll
        for (int n = 0; n < 4; ++n)
          acc[m][n] = __builtin_amdgcn_mfma_f32_16x16x32_bf16(af[m], bfr[n], acc[m][n], 0, 0, 0);
    }
  }
#pragma unroll
  for (int n = 0; n < 4; ++n) {
    int co = nb * 128 + wcol + n * 16 + (l & 15);
    float bias = b15[co];
#pragma unroll
    for (int m = 0; m < 4; ++m) {
      int prow = p0 + wrow + m * 16 + (l >> 4) * 4;
#pragma unroll
      for (int r = 0; r < 4; ++r)
        t1[(size_t)(prow + r) * 256 + co] = __float2bfloat16(acc[m][n][r] + bias);
    }
  }
}

// ---- GEMM2: feat[p][co] = sum t1*w51 + sum xT*w11 + b51+b11  -> featT bf16 NHWC
__global__ __launch_bounds__(256) void gemm2_kernel(
    const __hip_bfloat16* __restrict__ t1, const __hip_bfloat16* __restrict__ xT,
    const __hip_bfloat16* __restrict__ w2t,
    const float* __restrict__ b51, const float* __restrict__ b11,
    __hip_bfloat16* __restrict__ featT, const __hip_bfloat16* __restrict__ zbuf) {
  __shared__ __align__(16) char lds[32768];
  int bid = blockIdx.x;
  bid = (bid & 7) * (gridDim.x >> 3) + (bid >> 3);
  const int nb = bid & 1, mb = bid >> 1;
  const int p0 = mb * 128;
  const int tid = threadIdx.x, l = tid & 63, wid = tid >> 6;
  const int wrow = (wid >> 1) * 64, wcol = (wid & 1) * 64;
  const int sboff = (((l & 7) ^ (l >> 3)) << 4);

  int pbase[4], hv[4], cobase[4];
#pragma unroll
  for (int ii = 0; ii < 4; ++ii) {
    int is = wid * 4 + ii;
    pbase[ii] = p0 + is * 8 + (l >> 3);
    hv[ii] = (pbase[ii] / 192) % 192;
    cobase[ii] = nb * 128 + is * 8 + (l >> 3);
  }
  int a_ad[4][2], b_ad[4][2];
#pragma unroll
  for (int m = 0; m < 4; ++m)
#pragma unroll
    for (int kk = 0; kk < 2; ++kk) {
      int blk = ((kk * 4 + (l >> 4)) ^ (l & 7)) << 4;
      a_ad[m][kk] = (wrow + m * 16 + (l & 15)) * 128 + blk;
      b_ad[m][kk] = 16384 + (wcol + m * 16 + (l & 15)) * 128 + blk;
    }

  f32x4 acc[4][4] = {};
  const char* t1b = (const char*)t1;
  const char* xTb = (const char*)xT;
  const char* wB  = (const char*)w2t;
  const char* zb  = (const char*)zbuf;

  for (int kb = 0; kb < 24; ++kb) {
    __syncthreads();
#pragma unroll
    for (int ii = 0; ii < 4; ++ii) {
      int is = wid * 4 + ii;
      const char* src;
      if (kb < 20) {
        int k = kb >> 2, dl = k - 2;
        src = ((unsigned)(hv[ii] + dl) < 192u)
            ? t1b + (size_t)(pbase[ii] + dl * 192) * 512 + (kb & 3) * 128 + sboff
            : zb + sboff;
      } else {
        src = xTb + (size_t)pbase[ii] * 512 + (kb - 20) * 128 + sboff;
      }
      gload_lds16(src, lds + is * 1024);
      const char* bs = wB + (size_t)cobase[ii] * 3072 + kb * 128 + sboff;
      gload_lds16(bs, lds + 16384 + is * 1024);
    }
    __syncthreads();
#pragma unroll
    for (int kk = 0; kk < 2; ++kk) {
      bf16x8 af[4], bfr[4];
#pragma unroll
      for (int m = 0; m < 4; ++m) af[m] = *(const bf16x8*)(lds + a_ad[m][kk]);
#pragma unroll
      for (int n = 0; n < 4; ++n) bfr[n] = *(const bf16x8*)(lds + b_ad[n][kk]);
#pragma unroll
      for (int m = 0; m < 4; ++m)
#pragma unroll
        for (int n = 0; n < 4; ++n)
          acc[m][n] = __builtin_amdgcn_mfma_f32_16x16x32_bf16(af[m], bfr[n], acc[m][n], 0, 0, 0);
    }
  }
#pragma unroll
  for (int n = 0; n < 4; ++n) {
    int co = nb * 128 + wcol + n * 16 + (l & 15);
    float bias = b51[co] + b11[co];
#pragma unroll
    for (int m = 0; m < 4; ++m) {
      int prow = p0 + wrow + m * 16 + (l >> 4) * 4;
#pragma unroll
      for (int r = 0; r < 4; ++r)
        featT[(size_t)(prow + r) * 256 + co] = __float2bfloat16(acc[m][n][r] + bias);
    }
  }
}

// ---- out = x + feat + bilinear_gather(feat at box center); featT is bf16 NHWC.
// grid (P/256, C/64): blockIdx.y picks a 64-channel chunk -> 4x occupancy.
__global__ __launch_bounds__(256) void align_kernel(
    const float* __restrict__ x, const __hip_bfloat16* __restrict__ featT,
    const float* __restrict__ boxes, float* __restrict__ out) {
  int p = blockIdx.x * 256 + threadIdx.x;  // pixel
  int c0 = blockIdx.y * 64;                // channel chunk
  int b = p / HW_;
  int p2 = p - b * HW_;
  float yy = boxes[(size_t)p * 5 + 0] * SCALE;
  float xx = boxes[(size_t)p * 5 + 1] * SCALE;
  bool valid = (yy >= -1.0f) && (yy <= (float)H_) && (xx >= -1.0f) && (xx <= (float)W_);
  yy = fmaxf(yy, 0.f);
  xx = fmaxf(xx, 0.f);
  int yl = (int)floorf(yy), xl = (int)floorf(xx);
  int yh, xh;
  if (yl >= H_ - 1) { yl = H_ - 1; yh = H_ - 1; yy = (float)(H_ - 1); } else { yh = yl + 1; }
  if (xl >= W_ - 1) { xl = W_ - 1; xh = W_ - 1; xx = (float)(W_ - 1); } else { xh = xl + 1; }
  float ly = yy - (float)yl, lx = xx - (float)xl;
  float hy = 1.f - ly, hx = 1.f - lx;
  float q00 = hy * hx, q01 = hy * lx, q10 = ly * hx, q11 = ly * lx;
  if (!valid) { q00 = 0.f; q01 = 0.f; q10 = 0.f; q11 = 0.f; }
  const unsigned short* fT = (const unsigned short*)featT + (size_t)b * HW_ * C_;
  const unsigned short* f00 = fT + ((size_t)yl * W_ + xl) * C_ + c0;
  const unsigned short* f01 = fT + ((size_t)yl * W_ + xh) * C_ + c0;
  const unsigned short* f10 = fT + ((size_t)yh * W_ + xl) * C_ + c0;
  const unsigned short* f11 = fT + ((size_t)yh * W_ + xh) * C_ + c0;
  const unsigned short* fc  = fT + (size_t)p2 * C_ + c0;
  const float* xc = x + (size_t)b * CHW_ + p2;
  float* oc = out + (size_t)b * CHW_ + p2;
#pragma unroll
  for (int cc = 0; cc < 64; cc += 8) {
    uint4 A = *(const uint4*)(f00 + cc);
    uint4 Bv = *(const uint4*)(f01 + cc);
    uint4 Cv = *(const uint4*)(f10 + cc);
    uint4 D = *(const uint4*)(f11 + cc);
    uint4 E = *(const uint4*)(fc + cc);
    const unsigned int* aw = (const unsigned int*)&A;
    const unsigned int* bw = (const unsigned int*)&Bv;
    const unsigned int* cw = (const unsigned int*)&Cv;
    const unsigned int* dw = (const unsigned int*)&D;
    const unsigned int* ew = (const unsigned int*)&E;
#pragma unroll
    for (int w = 0; w < 4; ++w) {
      float a0 = __uint_as_float(aw[w] << 16), a1 = __uint_as_float(aw[w] & 0xffff0000u);
      float b0 = __uint_as_float(bw[w] << 16), b1 = __uint_as_float(bw[w] & 0xffff0000u);
      float c0f = __uint_as_float(cw[w] << 16), c1f = __uint_as_float(cw[w] & 0xffff0000u);
      float d0 = __uint_as_float(dw[w] << 16), d1 = __uint_as_float(dw[w] & 0xffff0000u);
      float e0 = __uint_as_float(ew[w] << 16), e1 = __uint_as_float(ew[w] & 0xffff0000u);
      float v0 = q00 * a0 + q01 * b0 + q10 * c0f + q11 * d0;
      float v1 = q00 * a1 + q01 * b1 + q10 * c1f + q11 * d1;
      int ch = c0 + cc + w * 2;
      oc[(size_t)ch * HW_]       = xc[(size_t)ch * HW_]       + e0 + v0;
      oc[(size_t)(ch + 1) * HW_] = xc[(size_t)(ch + 1) * HW_] + e1 + v1;
    }
  }
}

extern "C" void kernel_launch(void* const* d_in, const int* in_sizes, int n_in,
                              void* d_out, int out_size, void* d_ws, size_t ws_size,
                              hipStream_t stream) {
  const float* x     = (const float*)d_in[0];
  const float* boxes = (const float*)d_in[1];
  const float* w51   = (const float*)d_in[2];
  const float* b51   = (const float*)d_in[3];
  const float* w15   = (const float*)d_in[4];
  const float* b15   = (const float*)d_in[5];
  const float* w11   = (const float*)d_in[6];
  const float* b11   = (const float*)d_in[7];
  float* out = (float*)d_out;

  // d_ws: featT bf16 NHWC | w1t bf16 | w2t bf16 | zbuf   (~39.5 MB)
  __hip_bfloat16* featT = (__hip_bfloat16*)d_ws;
  __hip_bfloat16* w1t  = featT + (size_t)P_ * C_;
  __hip_bfloat16* w2t  = w1t + (size_t)C_ * 1280;
  __hip_bfloat16* zbuf = w2t + (size_t)C_ * 1536;
  // d_out doubles as scratch: t1 bf16 NHWC | xT bf16 NHWC (dead before align writes)
  __hip_bfloat16* t1 = (__hip_bfloat16*)d_out;
  __hip_bfloat16* xT = t1 + (size_t)P_ * C_;

  wtrans_kernel<<<dim3((C_ * C_ * 5 + 255) / 256), 256, 0, stream>>>(
      w15, w51, w11, w1t, w2t, zbuf);
  nchw2nhwc_kernel<<<dim3(HW_ / 32, C_ / 32, B_), dim3(32, 8), 0, stream>>>(x, xT);
  gemm1_kernel<<<dim3(P_ / 128 * 2), 256, 0, stream>>>(xT, w1t, b15, t1, zbuf);
  gemm2_kernel<<<dim3(P_ / 128 * 2), 256, 0, stream>>>(t1, xT, w2t, b51, b11, featT, zbuf);
  align_kernel<<<dim3(P_ / 256, C_ / 64), 256, 0, stream>>>(x, featT, boxes, out);
}

// Round 4
// 330.253 us; speedup vs baseline: 5.5753x; 1.0115x over previous
//
#include <hip/hip_runtime.h>
#include <hip/hip_bf16.h>
#include <stdint.h>

#define B_ 2
#define C_ 256
#define H_ 192
#define W_ 192
#define HW_ (H_*W_)
#define CHW_ (C_*HW_)
#define P_ (B_*HW_)
#define SCALE 0.125f

typedef __attribute__((ext_vector_type(8))) short bf16x8;
typedef __attribute__((ext_vector_type(4))) float f32x4;

__device__ __forceinline__ void gload_lds16(const void* g, void* l) {
  __builtin_amdgcn_global_load_lds(
      (const __attribute__((address_space(1))) uint32_t*)g,
      (__attribute__((address_space(3))) uint32_t*)l, 16, 0, 0);
}

// ---- weights: w15/w51 [co][ci][k] fp32 -> bf16 [co][k*256+ci]; w11 appended; zero zbuf
__global__ __launch_bounds__(256) void wtrans_kernel(
    const float* __restrict__ w15, const float* __restrict__ w51,
    const float* __restrict__ w11,
    __hip_bfloat16* __restrict__ w1t, __hip_bfloat16* __restrict__ w2t,
    __hip_bfloat16* __restrict__ zbuf) {
  int i = blockIdx.x * 256 + threadIdx.x;
  if (i < C_ * C_ * 5) {
    int co = i / (C_ * 5);
    int r  = i - co * (C_ * 5);
    int ci = r / 5;
    int k  = r - ci * 5;
    w1t[(size_t)co * 1280 + k * 256 + ci] = __float2bfloat16(w15[i]);
    w2t[(size_t)co * 1536 + k * 256 + ci] = __float2bfloat16(w51[i]);
  }
  if (i < C_ * C_) {
    int co = i >> 8, ci = i & 255;
    w2t[(size_t)co * 1536 + 1280 + ci] = __float2bfloat16(w11[i]);
  }
  if (i < 1024) zbuf[i] = __float2bfloat16(0.f);
}

// ---- x NCHW fp32 -> xT NHWC bf16 (LDS 32x32 tile transpose)
__global__ __launch_bounds__(256) void nchw2nhwc_kernel(
    const float* __restrict__ x, __hip_bfloat16* __restrict__ xT) {
  __shared__ float tile[32][33];
  int p0 = blockIdx.x * 32, c0 = blockIdx.y * 32, b = blockIdx.z;
  int tx = threadIdx.x, ty = threadIdx.y;
  const float* xb = x + (size_t)b * CHW_;
#pragma unroll
  for (int j = 0; j < 4; ++j)
    tile[ty + j * 8][tx] = xb[(size_t)(c0 + ty + j * 8) * HW_ + p0 + tx];
  __syncthreads();
  __hip_bfloat16* xo = xT + (size_t)b * HW_ * C_;
#pragma unroll
  for (int j = 0; j < 4; ++j)
    xo[(size_t)(p0 + ty + j * 8) * C_ + c0 + tx] = __float2bfloat16(tile[tx][ty + j * 8]);
}

// ---- GEMM1: t1[p][co] = bf16( sum_{k,ci} xT[p+(k-2)][ci] * w15[co][ci][k] + b15[co] )
__global__ __launch_bounds__(256) void gemm1_kernel(
    const __hip_bfloat16* __restrict__ xT, const __hip_bfloat16* __restrict__ w1t,
    const float* __restrict__ b15, __hip_bfloat16* __restrict__ t1,
    const __hip_bfloat16* __restrict__ zbuf) {
  __shared__ __align__(16) char lds[32768];  // A: [0,16K)  B: [16K,32K)
  int bid = blockIdx.x;
  bid = (bid & 7) * (gridDim.x >> 3) + (bid >> 3);  // XCD swizzle (1152 % 8 == 0)
  const int nb = bid & 1, mb = bid >> 1;
  const int p0 = mb * 128;
  const int tid = threadIdx.x, l = tid & 63, wid = tid >> 6;
  const int wrow = (wid >> 1) * 64, wcol = (wid & 1) * 64;
  const int sboff = (((l & 7) ^ (l >> 3)) << 4);

  int pbase[4], wv[4], cobase[4];
#pragma unroll
  for (int ii = 0; ii < 4; ++ii) {
    int is = wid * 4 + ii;
    pbase[ii] = p0 + is * 8 + (l >> 3);
    wv[ii] = pbase[ii] % 192;
    cobase[ii] = nb * 128 + is * 8 + (l >> 3);
  }
  int a_ad[4][2], b_ad[4][2];
#pragma unroll
  for (int m = 0; m < 4; ++m)
#pragma unroll
    for (int kk = 0; kk < 2; ++kk) {
      int blk = ((kk * 4 + (l >> 4)) ^ (l & 7)) << 4;
      a_ad[m][kk] = (wrow + m * 16 + (l & 15)) * 128 + blk;
      b_ad[m][kk] = 16384 + (wcol + m * 16 + (l & 15)) * 128 + blk;
    }

  f32x4 acc[4][4] = {};
  const char* xTb = (const char*)xT;
  const char* wB  = (const char*)w1t;
  const char* zb  = (const char*)zbuf;

  for (int kb = 0; kb < 20; ++kb) {
    int k = kb >> 2, dl = k - 2;
    int cib = (kb & 3) * 128;
    __syncthreads();
#pragma unroll
    for (int ii = 0; ii < 4; ++ii) {
      int is = wid * 4 + ii;
      const char* src = ((unsigned)(wv[ii] + dl) < 192u)
          ? xTb + (size_t)(pbase[ii] + dl) * 512 + cib + sboff
          : zb + sboff;
      gload_lds16(src, lds + is * 1024);
      const char* bs = wB + (size_t)cobase[ii] * 2560 + kb * 128 + sboff;
      gload_lds16(bs, lds + 16384 + is * 1024);
    }
    __syncthreads();
#pragma unroll
    for (int kk = 0; kk < 2; ++kk) {
      bf16x8 af[4], bfr[4];
#pragma unroll
      for (int m = 0; m < 4; ++m) af[m] = *(const bf16x8*)(lds + a_ad[m][kk]);
#pragma unroll
      for (int n = 0; n < 4; ++n) bfr[n] = *(const bf16x8*)(lds + b_ad[n][kk]);
#pragma unroll
      for (int m = 0; m < 4; ++m)
#pragma unroll
        for (int n = 0; n < 4; ++n)
          acc[m][n] = __builtin_amdgcn_mfma_f32_16x16x32_bf16(af[m], bfr[n], acc[m][n], 0, 0, 0);
    }
  }
#pragma unroll
  for (int n = 0; n < 4; ++n) {
    int co = nb * 128 + wcol + n * 16 + (l & 15);
    float bias = b15[co];
#pragma unroll
    for (int m = 0; m < 4; ++m) {
      int prow = p0 + wrow + m * 16 + (l >> 4) * 4;
#pragma unroll
      for (int r = 0; r < 4; ++r)
        t1[(size_t)(prow + r) * 256 + co] = __float2bfloat16(acc[m][n][r] + bias);
    }
  }
}

// ---- GEMM2: feat[p][co] = sum t1*w51 + sum xT*w11 + b51+b11  -> featT bf16 NHWC
__global__ __launch_bounds__(256) void gemm2_kernel(
    const __hip_bfloat16* __restrict__ t1, const __hip_bfloat16* __restrict__ xT,
    const __hip_bfloat16* __restrict__ w2t,
    const float* __restrict__ b51, const float* __restrict__ b11,
    __hip_bfloat16* __restrict__ featT, const __hip_bfloat16* __restrict__ zbuf) {
  __shared__ __align__(16) char lds[32768];
  int bid = blockIdx.x;
  bid = (bid & 7) * (gridDim.x >> 3) + (bid >> 3);
  const int nb = bid & 1, mb = bid >> 1;
  const int p0 = mb * 128;
  const int tid = threadIdx.x, l = tid & 63, wid = tid >> 6;
  const int wrow = (wid >> 1) * 64, wcol = (wid & 1) * 64;
  const int sboff = (((l & 7) ^ (l >> 3)) << 4);

  int pbase[4], hv[4], cobase[4];
#pragma unroll
  for (int ii = 0; ii < 4; ++ii) {
    int is = wid * 4 + ii;
    pbase[ii] = p0 + is * 8 + (l >> 3);
    hv[ii] = (pbase[ii] / 192) % 192;
    cobase[ii] = nb * 128 + is * 8 + (l >> 3);
  }
  int a_ad[4][2], b_ad[4][2];
#pragma unroll
  for (int m = 0; m < 4; ++m)
#pragma unroll
    for (int kk = 0; kk < 2; ++kk) {
      int blk = ((kk * 4 + (l >> 4)) ^ (l & 7)) << 4;
      a_ad[m][kk] = (wrow + m * 16 + (l & 15)) * 128 + blk;
      b_ad[m][kk] = 16384 + (wcol + m * 16 + (l & 15)) * 128 + blk;
    }

  f32x4 acc[4][4] = {};
  const char* t1b = (const char*)t1;
  const char* xTb = (const char*)xT;
  const char* wB  = (const char*)w2t;
  const char* zb  = (const char*)zbuf;

  for (int kb = 0; kb < 24; ++kb) {
    __syncthreads();
#pragma unroll
    for (int ii = 0; ii < 4; ++ii) {
      int is = wid * 4 + ii;
      const char* src;
      if (kb < 20) {
        int k = kb >> 2, dl = k - 2;
        src = ((unsigned)(hv[ii] + dl) < 192u)
            ? t1b + (size_t)(pbase[ii] + dl * 192) * 512 + (kb & 3) * 128 + sboff
            : zb + sboff;
      } else {
        src = xTb + (size_t)pbase[ii] * 512 + (kb - 20) * 128 + sboff;
      }
      gload_lds16(src, lds + is * 1024);
      const char* bs = wB + (size_t)cobase[ii] * 3072 + kb * 128 + sboff;
      gload_lds16(bs, lds + 16384 + is * 1024);
    }
    __syncthreads();
#pragma unroll
    for (int kk = 0; kk < 2; ++kk) {
      bf16x8 af[4], bfr[4];
#pragma unroll
      for (int m = 0; m < 4; ++m) af[m] = *(const bf16x8*)(lds + a_ad[m][kk]);
#pragma unroll
      for (int n = 0; n < 4; ++n) bfr[n] = *(const bf16x8*)(lds + b_ad[n][kk]);
#pragma unroll
      for (int m = 0; m < 4; ++m)
#pragma unroll
        for (int n = 0; n < 4; ++n)
          acc[m][n] = __builtin_amdgcn_mfma_f32_16x16x32_bf16(af[m], bfr[n], acc[m][n], 0, 0, 0);
    }
  }
#pragma unroll
  for (int n = 0; n < 4; ++n) {
    int co = nb * 128 + wcol + n * 16 + (l & 15);
    float bias = b51[co] + b11[co];
#pragma unroll
    for (int m = 0; m < 4; ++m) {
      int prow = p0 + wrow + m * 16 + (l >> 4) * 4;
#pragma unroll
      for (int r = 0; r < 4; ++r)
        featT[(size_t)(prow + r) * 256 + co] = __float2bfloat16(acc[m][n][r] + bias);
    }
  }
}

// ---- out = x + feat + bilinear_gather(feat); all bf16 NHWC reads, fp32 NCHW writes.
// grid (P/64, C/128): 1-wave blocks, 256B-granule-aligned gather chunks.
__global__ __launch_bounds__(64) void align_kernel(
    const __hip_bfloat16* __restrict__ xT, const __hip_bfloat16* __restrict__ featT,
    const float* __restrict__ boxes, float* __restrict__ out) {
  int p = blockIdx.x * 64 + threadIdx.x;  // pixel
  int c0 = blockIdx.y * 128;              // channel chunk (256B of bf16 row)
  int b = p / HW_;
  int p2 = p - b * HW_;
  float yy = boxes[(size_t)p * 5 + 0] * SCALE;
  float xx = boxes[(size_t)p * 5 + 1] * SCALE;
  bool valid = (yy >= -1.0f) && (yy <= (float)H_) && (xx >= -1.0f) && (xx <= (float)W_);
  yy = fmaxf(yy, 0.f);
  xx = fmaxf(xx, 0.f);
  int yl = (int)floorf(yy), xl = (int)floorf(xx);
  int yh, xh;
  if (yl >= H_ - 1) { yl = H_ - 1; yh = H_ - 1; yy = (float)(H_ - 1); } else { yh = yl + 1; }
  if (xl >= W_ - 1) { xl = W_ - 1; xh = W_ - 1; xx = (float)(W_ - 1); } else { xh = xl + 1; }
  float ly = yy - (float)yl, lx = xx - (float)xl;
  float hy = 1.f - ly, hx = 1.f - lx;
  float q00 = hy * hx, q01 = hy * lx, q10 = ly * hx, q11 = ly * lx;
  if (!valid) { q00 = 0.f; q01 = 0.f; q10 = 0.f; q11 = 0.f; }
  const unsigned short* fT = (const unsigned short*)featT + (size_t)b * HW_ * C_;
  const unsigned short* xb = (const unsigned short*)xT + (size_t)b * HW_ * C_;
  const unsigned short* f00 = fT + ((size_t)yl * W_ + xl) * C_ + c0;
  const unsigned short* f01 = fT + ((size_t)yl * W_ + xh) * C_ + c0;
  const unsigned short* f10 = fT + ((size_t)yh * W_ + xl) * C_ + c0;
  const unsigned short* f11 = fT + ((size_t)yh * W_ + xh) * C_ + c0;
  const unsigned short* fc  = fT + (size_t)p2 * C_ + c0;
  const unsigned short* xc  = xb + (size_t)p2 * C_ + c0;
  float* oc = out + (size_t)b * CHW_ + p2;
#pragma unroll
  for (int cc = 0; cc < 128; cc += 8) {
    uint4 A = *(const uint4*)(f00 + cc);
    uint4 Bv = *(const uint4*)(f01 + cc);
    uint4 Cv = *(const uint4*)(f10 + cc);
    uint4 D = *(const uint4*)(f11 + cc);
    uint4 E = *(const uint4*)(fc + cc);
    uint4 X = *(const uint4*)(xc + cc);
    const unsigned int* aw = (const unsigned int*)&A;
    const unsigned int* bw = (const unsigned int*)&Bv;
    const unsigned int* cw = (const unsigned int*)&Cv;
    const unsigned int* dw = (const unsigned int*)&D;
    const unsigned int* ew = (const unsigned int*)&E;
    const unsigned int* xw = (const unsigned int*)&X;
#pragma unroll
    for (int w = 0; w < 4; ++w) {
      float a0 = __uint_as_float(aw[w] << 16), a1 = __uint_as_float(aw[w] & 0xffff0000u);
      float b0 = __uint_as_float(bw[w] << 16), b1 = __uint_as_float(bw[w] & 0xffff0000u);
      float c0f = __uint_as_float(cw[w] << 16), c1f = __uint_as_float(cw[w] & 0xffff0000u);
      float d0 = __uint_as_float(dw[w] << 16), d1 = __uint_as_float(dw[w] & 0xffff0000u);
      float e0 = __uint_as_float(ew[w] << 16), e1 = __uint_as_float(ew[w] & 0xffff0000u);
      float x0 = __uint_as_float(xw[w] << 16), x1 = __uint_as_float(xw[w] & 0xffff0000u);
      float v0 = q00 * a0 + q01 * b0 + q10 * c0f + q11 * d0;
      float v1 = q00 * a1 + q01 * b1 + q10 * c1f + q11 * d1;
      int ch = c0 + cc + w * 2;
      __builtin_nontemporal_store(x0 + e0 + v0, &oc[(size_t)ch * HW_]);
      __builtin_nontemporal_store(x1 + e1 + v1, &oc[(size_t)(ch + 1) * HW_]);
    }
  }
}

extern "C" void kernel_launch(void* const* d_in, const int* in_sizes, int n_in,
                              void* d_out, int out_size, void* d_ws, size_t ws_size,
                              hipStream_t stream) {
  const float* x     = (const float*)d_in[0];
  const float* boxes = (const float*)d_in[1];
  const float* w51   = (const float*)d_in[2];
  const float* b51   = (const float*)d_in[3];
  const float* w15   = (const float*)d_in[4];
  const float* b15   = (const float*)d_in[5];
  const float* w11   = (const float*)d_in[6];
  const float* b11   = (const float*)d_in[7];
  float* out = (float*)d_out;

  // d_ws: featT bf16 NHWC | xT bf16 NHWC | w1t | w2t | zbuf  (~77 MB)
  __hip_bfloat16* featT = (__hip_bfloat16*)d_ws;
  __hip_bfloat16* xT   = featT + (size_t)P_ * C_;
  __hip_bfloat16* w1t  = xT + (size_t)P_ * C_;
  __hip_bfloat16* w2t  = w1t + (size_t)C_ * 1280;
  __hip_bfloat16* zbuf = w2t + (size_t)C_ * 1536;
  // d_out doubles as scratch for t1 (dead before align writes out)
  __hip_bfloat16* t1 = (__hip_bfloat16*)d_out;

  wtrans_kernel<<<dim3((C_ * C_ * 5 + 255) / 256), 256, 0, stream>>>(
      w15, w51, w11, w1t, w2t, zbuf);
  nchw2nhwc_kernel<<<dim3(HW_ / 32, C_ / 32, B_), dim3(32, 8), 0, stream>>>(x, xT);
  gemm1_kernel<<<dim3(P_ / 128 * 2), 256, 0, stream>>>(xT, w1t, b15, t1, zbuf);
  gemm2_kernel<<<dim3(P_ / 128 * 2), 256, 0, stream>>>(t1, xT, w2t, b51, b11, featT, zbuf);
  align_kernel<<<dim3(P_ / 64, C_ / 128), 64, 0, stream>>>(xT, featT, boxes, out);
}

// Round 5
// 219.495 us; speedup vs baseline: 8.3886x; 1.5046x over previous
//
#include <hip/hip_runtime.h>
#include <hip/hip_bf16.h>
#include <stdint.h>

#define B_ 2
#define C_ 256
#define H_ 192
#define W_ 192
#define HW_ (H_*W_)
#define CHW_ (C_*HW_)
#define P_ (B_*HW_)
#define SCALE 0.125f

typedef __attribute__((ext_vector_type(8))) short bf16x8;
typedef __attribute__((ext_vector_type(4))) float f32x4;

__device__ __forceinline__ void gload_lds16(const void* g, void* l) {
  __builtin_amdgcn_global_load_lds(
      (const __attribute__((address_space(1))) uint32_t*)g,
      (__attribute__((address_space(3))) uint32_t*)l, 16, 0, 0);
}

// ---- weights: w15/w51 [co][ci][k] fp32 -> bf16 [co][k*256+ci]; w11 appended; zero zbuf
__global__ __launch_bounds__(256) void wtrans_kernel(
    const float* __restrict__ w15, const float* __restrict__ w51,
    const float* __restrict__ w11,
    __hip_bfloat16* __restrict__ w1t, __hip_bfloat16* __restrict__ w2t,
    __hip_bfloat16* __restrict__ zbuf) {
  int i = blockIdx.x * 256 + threadIdx.x;
  if (i < C_ * C_ * 5) {
    int co = i / (C_ * 5);
    int r  = i - co * (C_ * 5);
    int ci = r / 5;
    int k  = r - ci * 5;
    w1t[(size_t)co * 1280 + k * 256 + ci] = __float2bfloat16(w15[i]);
    w2t[(size_t)co * 1536 + k * 256 + ci] = __float2bfloat16(w51[i]);
  }
  if (i < C_ * C_) {
    int co = i >> 8, ci = i & 255;
    w2t[(size_t)co * 1536 + 1280 + ci] = __float2bfloat16(w11[i]);
  }
  if (i < 1024) zbuf[i] = __float2bfloat16(0.f);
}

// ---- x NCHW fp32 -> xT NHWC bf16 (LDS 32x32 tile transpose)
__global__ __launch_bounds__(256) void nchw2nhwc_kernel(
    const float* __restrict__ x, __hip_bfloat16* __restrict__ xT) {
  __shared__ float tile[32][33];
  int p0 = blockIdx.x * 32, c0 = blockIdx.y * 32, b = blockIdx.z;
  int tx = threadIdx.x, ty = threadIdx.y;
  const float* xb = x + (size_t)b * CHW_;
#pragma unroll
  for (int j = 0; j < 4; ++j)
    tile[ty + j * 8][tx] = xb[(size_t)(c0 + ty + j * 8) * HW_ + p0 + tx];
  __syncthreads();
  __hip_bfloat16* xo = xT + (size_t)b * HW_ * C_;
#pragma unroll
  for (int j = 0; j < 4; ++j)
    xo[(size_t)(p0 + ty + j * 8) * C_ + c0 + tx] = __float2bfloat16(tile[tx][ty + j * 8]);
}

// ---- GEMM1: t1[p][co] = bf16( sum_{k,ci} xT[p+(k-2)][ci] * w15[co][ci][k] + b15[co] )
__global__ __launch_bounds__(256) void gemm1_kernel(
    const __hip_bfloat16* __restrict__ xT, const __hip_bfloat16* __restrict__ w1t,
    const float* __restrict__ b15, __hip_bfloat16* __restrict__ t1,
    const __hip_bfloat16* __restrict__ zbuf) {
  __shared__ __align__(16) char lds[32768];  // A: [0,16K)  B: [16K,32K)
  int bid = blockIdx.x;
  bid = (bid & 7) * (gridDim.x >> 3) + (bid >> 3);  // XCD swizzle (1152 % 8 == 0)
  const int nb = bid & 1, mb = bid >> 1;
  const int p0 = mb * 128;
  const int tid = threadIdx.x, l = tid & 63, wid = tid >> 6;
  const int wrow = (wid >> 1) * 64, wcol = (wid & 1) * 64;
  const int sboff = (((l & 7) ^ (l >> 3)) << 4);

  int pbase[4], wv[4], cobase[4];
#pragma unroll
  for (int ii = 0; ii < 4; ++ii) {
    int is = wid * 4 + ii;
    pbase[ii] = p0 + is * 8 + (l >> 3);
    wv[ii] = pbase[ii] % 192;
    cobase[ii] = nb * 128 + is * 8 + (l >> 3);
  }
  int a_ad[4][2], b_ad[4][2];
#pragma unroll
  for (int m = 0; m < 4; ++m)
#pragma unroll
    for (int kk = 0; kk < 2; ++kk) {
      int blk = ((kk * 4 + (l >> 4)) ^ (l & 7)) << 4;
      a_ad[m][kk] = (wrow + m * 16 + (l & 15)) * 128 + blk;
      b_ad[m][kk] = 16384 + (wcol + m * 16 + (l & 15)) * 128 + blk;
    }

  f32x4 acc[4][4] = {};
  const char* xTb = (const char*)xT;
  const char* wB  = (const char*)w1t;
  const char* zb  = (const char*)zbuf;

  for (int kb = 0; kb < 20; ++kb) {
    int k = kb >> 2, dl = k - 2;
    int cib = (kb & 3) * 128;
    __syncthreads();
#pragma unroll
    for (int ii = 0; ii < 4; ++ii) {
      int is = wid * 4 + ii;
      const char* src = ((unsigned)(wv[ii] + dl) < 192u)
          ? xTb + (size_t)(pbase[ii] + dl) * 512 + cib + sboff
          : zb + sboff;
      gload_lds16(src, lds + is * 1024);
      const char* bs = wB + (size_t)cobase[ii] * 2560 + kb * 128 + sboff;
      gload_lds16(bs, lds + 16384 + is * 1024);
    }
    __syncthreads();
#pragma unroll
    for (int kk = 0; kk < 2; ++kk) {
      bf16x8 af[4], bfr[4];
#pragma unroll
      for (int m = 0; m < 4; ++m) af[m] = *(const bf16x8*)(lds + a_ad[m][kk]);
#pragma unroll
      for (int n = 0; n < 4; ++n) bfr[n] = *(const bf16x8*)(lds + b_ad[n][kk]);
#pragma unroll
      for (int m = 0; m < 4; ++m)
#pragma unroll
        for (int n = 0; n < 4; ++n)
          acc[m][n] = __builtin_amdgcn_mfma_f32_16x16x32_bf16(af[m], bfr[n], acc[m][n], 0, 0, 0);
    }
  }
#pragma unroll
  for (int n = 0; n < 4; ++n) {
    int co = nb * 128 + wcol + n * 16 + (l & 15);
    float bias = b15[co];
#pragma unroll
    for (int m = 0; m < 4; ++m) {
      int prow = p0 + wrow + m * 16 + (l >> 4) * 4;
#pragma unroll
      for (int r = 0; r < 4; ++r)
        t1[(size_t)(prow + r) * 256 + co] = __float2bfloat16(acc[m][n][r] + bias);
    }
  }
}

// ---- GEMM2: feat[p][co] = sum t1*w51 + sum xT*w11 + b51+b11  -> featT bf16 NHWC
__global__ __launch_bounds__(256) void gemm2_kernel(
    const __hip_bfloat16* __restrict__ t1, const __hip_bfloat16* __restrict__ xT,
    const __hip_bfloat16* __restrict__ w2t,
    const float* __restrict__ b51, const float* __restrict__ b11,
    __hip_bfloat16* __restrict__ featT, const __hip_bfloat16* __restrict__ zbuf) {
  __shared__ __align__(16) char lds[32768];
  int bid = blockIdx.x;
  bid = (bid & 7) * (gridDim.x >> 3) + (bid >> 3);
  const int nb = bid & 1, mb = bid >> 1;
  const int p0 = mb * 128;
  const int tid = threadIdx.x, l = tid & 63, wid = tid >> 6;
  const int wrow = (wid >> 1) * 64, wcol = (wid & 1) * 64;
  const int sboff = (((l & 7) ^ (l >> 3)) << 4);

  int pbase[4], hv[4], cobase[4];
#pragma unroll
  for (int ii = 0; ii < 4; ++ii) {
    int is = wid * 4 + ii;
    pbase[ii] = p0 + is * 8 + (l >> 3);
    hv[ii] = (pbase[ii] / 192) % 192;
    cobase[ii] = nb * 128 + is * 8 + (l >> 3);
  }
  int a_ad[4][2], b_ad[4][2];
#pragma unroll
  for (int m = 0; m < 4; ++m)
#pragma unroll
    for (int kk = 0; kk < 2; ++kk) {
      int blk = ((kk * 4 + (l >> 4)) ^ (l & 7)) << 4;
      a_ad[m][kk] = (wrow + m * 16 + (l & 15)) * 128 + blk;
      b_ad[m][kk] = 16384 + (wcol + m * 16 + (l & 15)) * 128 + blk;
    }

  f32x4 acc[4][4] = {};
  const char* t1b = (const char*)t1;
  const char* xTb = (const char*)xT;
  const char* wB  = (const char*)w2t;
  const char* zb  = (const char*)zbuf;

  for (int kb = 0; kb < 24; ++kb) {
    __syncthreads();
#pragma unroll
    for (int ii = 0; ii < 4; ++ii) {
      int is = wid * 4 + ii;
      const char* src;
      if (kb < 20) {
        int k = kb >> 2, dl = k - 2;
        src = ((unsigned)(hv[ii] + dl) < 192u)
            ? t1b + (size_t)(pbase[ii] + dl * 192) * 512 + (kb & 3) * 128 + sboff
            : zb + sboff;
      } else {
        src = xTb + (size_t)pbase[ii] * 512 + (kb - 20) * 128 + sboff;
      }
      gload_lds16(src, lds + is * 1024);
      const char* bs = wB + (size_t)cobase[ii] * 3072 + kb * 128 + sboff;
      gload_lds16(bs, lds + 16384 + is * 1024);
    }
    __syncthreads();
#pragma unroll
    for (int kk = 0; kk < 2; ++kk) {
      bf16x8 af[4], bfr[4];
#pragma unroll
      for (int m = 0; m < 4; ++m) af[m] = *(const bf16x8*)(lds + a_ad[m][kk]);
#pragma unroll
      for (int n = 0; n < 4; ++n) bfr[n] = *(const bf16x8*)(lds + b_ad[n][kk]);
#pragma unroll
      for (int m = 0; m < 4; ++m)
#pragma unroll
        for (int n = 0; n < 4; ++n)
          acc[m][n] = __builtin_amdgcn_mfma_f32_16x16x32_bf16(af[m], bfr[n], acc[m][n], 0, 0, 0);
    }
  }
#pragma unroll
  for (int n = 0; n < 4; ++n) {
    int co = nb * 128 + wcol + n * 16 + (l & 15);
    float bias = b51[co] + b11[co];
#pragma unroll
    for (int m = 0; m < 4; ++m) {
      int prow = p0 + wrow + m * 16 + (l >> 4) * 4;
#pragma unroll
      for (int r = 0; r < 4; ++r)
        featT[(size_t)(prow + r) * 256 + co] = __float2bfloat16(acc[m][n][r] + bias);
    }
  }
}

// ---- out = x + feat + bilinear_gather(feat).
// Block = 256 thr / 32 pixels. Phase A: lane=channel, each corner row is ONE
// 512B fully-consumed load; result staged in LDS. Phase B: lane=pixel,
// coalesced NCHW NT stores.
__global__ __launch_bounds__(256) void align_kernel(
    const __hip_bfloat16* __restrict__ xT, const __hip_bfloat16* __restrict__ featT,
    const float* __restrict__ boxes, float* __restrict__ out) {
  __shared__ float vs[32][258];  // [pixel][channel], +2 pad (phase-B 4-way max)
  const int tid = threadIdx.x, l = tid & 63, wv = tid >> 6;
  const int p0 = blockIdx.x * 32;

#pragma unroll 4
  for (int i = 0; i < 8; ++i) {
    int pl = wv * 8 + i;
    int p = p0 + pl;
    int b = p / HW_;
    int p2 = p - b * HW_;
    float yy = boxes[(size_t)p * 5 + 0] * SCALE;
    float xx = boxes[(size_t)p * 5 + 1] * SCALE;
    bool valid = (yy >= -1.0f) && (yy <= (float)H_) && (xx >= -1.0f) && (xx <= (float)W_);
    yy = fmaxf(yy, 0.f);
    xx = fmaxf(xx, 0.f);
    int yl = (int)floorf(yy), xl = (int)floorf(xx);
    int yh, xh;
    if (yl >= H_ - 1) { yl = H_ - 1; yh = H_ - 1; yy = (float)(H_ - 1); } else { yh = yl + 1; }
    if (xl >= W_ - 1) { xl = W_ - 1; xh = W_ - 1; xx = (float)(W_ - 1); } else { xh = xl + 1; }
    float ly = yy - (float)yl, lx = xx - (float)xl;
    float hy = 1.f - ly, hx = 1.f - lx;
    float q00 = hy * hx, q01 = hy * lx, q10 = ly * hx, q11 = ly * lx;
    if (!valid) { q00 = 0.f; q01 = 0.f; q10 = 0.f; q11 = 0.f; }
    const unsigned short* fT = (const unsigned short*)featT + (size_t)b * HW_ * C_;
    const unsigned short* xb = (const unsigned short*)xT + (size_t)b * HW_ * C_;
    int co = l * 4;  // this lane's 4 channels
    uint2 A  = *(const uint2*)(fT + ((size_t)yl * W_ + xl) * C_ + co);
    uint2 Bv = *(const uint2*)(fT + ((size_t)yl * W_ + xh) * C_ + co);
    uint2 Cv = *(const uint2*)(fT + ((size_t)yh * W_ + xl) * C_ + co);
    uint2 D  = *(const uint2*)(fT + ((size_t)yh * W_ + xh) * C_ + co);
    uint2 E  = *(const uint2*)(fT + (size_t)p2 * C_ + co);
    uint2 X  = *(const uint2*)(xb + (size_t)p2 * C_ + co);
    float o[4];
#pragma unroll
    for (int w = 0; w < 2; ++w) {
      unsigned int aw = (&A.x)[w], bw = (&Bv.x)[w], cw = (&Cv.x)[w],
                   dw = (&D.x)[w], ew = (&E.x)[w], xw = (&X.x)[w];
      float a0 = __uint_as_float(aw << 16), a1 = __uint_as_float(aw & 0xffff0000u);
      float b0 = __uint_as_float(bw << 16), b1 = __uint_as_float(bw & 0xffff0000u);
      float c0 = __uint_as_float(cw << 16), c1 = __uint_as_float(cw & 0xffff0000u);
      float d0 = __uint_as_float(dw << 16), d1 = __uint_as_float(dw & 0xffff0000u);
      float e0 = __uint_as_float(ew << 16), e1 = __uint_as_float(ew & 0xffff0000u);
      float x0 = __uint_as_float(xw << 16), x1 = __uint_as_float(xw & 0xffff0000u);
      o[w * 2 + 0] = x0 + e0 + q00 * a0 + q01 * b0 + q10 * c0 + q11 * d0;
      o[w * 2 + 1] = x1 + e1 + q00 * a1 + q01 * b1 + q10 * c1 + q11 * d1;
    }
    *(float2*)&vs[pl][co]     = make_float2(o[0], o[1]);
    *(float2*)&vs[pl][co + 2] = make_float2(o[2], o[3]);
  }
  __syncthreads();

  // Phase B: lane=pixel, coalesced NCHW writes
  const int pl = tid & 31, cg = tid >> 5;
  const int p = p0 + pl;
  const int b = p / HW_;
  const int p2 = p - b * HW_;
  float* oc = out + (size_t)b * CHW_ + p2;
#pragma unroll
  for (int j = 0; j < 32; ++j) {
    int ch = cg * 32 + j;
    __builtin_nontemporal_store(vs[pl][ch], &oc[(size_t)ch * HW_]);
  }
}

extern "C" void kernel_launch(void* const* d_in, const int* in_sizes, int n_in,
                              void* d_out, int out_size, void* d_ws, size_t ws_size,
                              hipStream_t stream) {
  const float* x     = (const float*)d_in[0];
  const float* boxes = (const float*)d_in[1];
  const float* w51   = (const float*)d_in[2];
  const float* b51   = (const float*)d_in[3];
  const float* w15   = (const float*)d_in[4];
  const float* b15   = (const float*)d_in[5];
  const float* w11   = (const float*)d_in[6];
  const float* b11   = (const float*)d_in[7];
  float* out = (float*)d_out;

  // d_ws: featT bf16 NHWC | xT bf16 NHWC | w1t | w2t | zbuf  (~77 MB)
  __hip_bfloat16* featT = (__hip_bfloat16*)d_ws;
  __hip_bfloat16* xT   = featT + (size_t)P_ * C_;
  __hip_bfloat16* w1t  = xT + (size_t)P_ * C_;
  __hip_bfloat16* w2t  = w1t + (size_t)C_ * 1280;
  __hip_bfloat16* zbuf = w2t + (size_t)C_ * 1536;
  // d_out doubles as scratch for t1 (dead before align writes out)
  __hip_bfloat16* t1 = (__hip_bfloat16*)d_out;

  wtrans_kernel<<<dim3((C_ * C_ * 5 + 255) / 256), 256, 0, stream>>>(
      w15, w51, w11, w1t, w2t, zbuf);
  nchw2nhwc_kernel<<<dim3(HW_ / 32, C_ / 32, B_), dim3(32, 8), 0, stream>>>(x, xT);
  gemm1_kernel<<<dim3(P_ / 128 * 2), 256, 0, stream>>>(xT, w1t, b15, t1, zbuf);
  gemm2_kernel<<<dim3(P_ / 128 * 2), 256, 0, stream>>>(t1, xT, w2t, b51, b11, featT, zbuf);
  align_kernel<<<dim3(P_ / 32), 256, 0, stream>>>(xT, featT, boxes, out);
}

// Round 6
// 173.170 us; speedup vs baseline: 10.6327x; 1.2675x over previous
//
#include <hip/hip_runtime.h>
#include <hip/hip_bf16.h>
#include <stdint.h>

#define B_ 2
#define C_ 256
#define H_ 192
#define W_ 192
#define HW_ (H_*W_)
#define CHW_ (C_*HW_)
#define P_ (B_*HW_)
#define SCALE 0.125f

typedef __attribute__((ext_vector_type(8))) short bf16x8;
typedef __attribute__((ext_vector_type(4))) float f32x4;

__device__ __forceinline__ void gload_lds16(const void* g, void* l) {
  __builtin_amdgcn_global_load_lds(
      (const __attribute__((address_space(1))) uint32_t*)g,
      (__attribute__((address_space(3))) uint32_t*)l, 16, 0, 0);
}

// ---- weights: w15/w51 [co][ci][k] fp32 -> bf16 [co][k*256+ci]; w11 appended; zero zbuf
__global__ __launch_bounds__(256) void wtrans_kernel(
    const float* __restrict__ w15, const float* __restrict__ w51,
    const float* __restrict__ w11,
    __hip_bfloat16* __restrict__ w1t, __hip_bfloat16* __restrict__ w2t,
    __hip_bfloat16* __restrict__ zbuf) {
  int i = blockIdx.x * 256 + threadIdx.x;
  if (i < C_ * C_ * 5) {
    int co = i / (C_ * 5);
    int r  = i - co * (C_ * 5);
    int ci = r / 5;
    int k  = r - ci * 5;
    w1t[(size_t)co * 1280 + k * 256 + ci] = __float2bfloat16(w15[i]);
    w2t[(size_t)co * 1536 + k * 256 + ci] = __float2bfloat16(w51[i]);
  }
  if (i < C_ * C_) {
    int co = i >> 8, ci = i & 255;
    w2t[(size_t)co * 1536 + 1280 + ci] = __float2bfloat16(w11[i]);
  }
  if (i < 1024) zbuf[i] = __float2bfloat16(0.f);
}

// ---- x NCHW fp32 -> xT NHWC bf16 (LDS 32x32 tile transpose)
__global__ __launch_bounds__(256) void nchw2nhwc_kernel(
    const float* __restrict__ x, __hip_bfloat16* __restrict__ xT) {
  __shared__ float tile[32][33];
  int p0 = blockIdx.x * 32, c0 = blockIdx.y * 32, b = blockIdx.z;
  int tx = threadIdx.x, ty = threadIdx.y;
  const float* xb = x + (size_t)b * CHW_;
#pragma unroll
  for (int j = 0; j < 4; ++j)
    tile[ty + j * 8][tx] = xb[(size_t)(c0 + ty + j * 8) * HW_ + p0 + tx];
  __syncthreads();
  __hip_bfloat16* xo = xT + (size_t)b * HW_ * C_;
#pragma unroll
  for (int j = 0; j < 4; ++j)
    xo[(size_t)(p0 + ty + j * 8) * C_ + c0 + tx] = __float2bfloat16(tile[tx][ty + j * 8]);
}

// ---- GEMM1: t1[p][co] = bf16(conv1x5(xT)+b15). Tile = one h-row (192 px) x 128 co.
// A staged once per 64-ci block with +/-2 w-halo (halo rows are true zeros);
// taps k=0..4 are LDS row offsets. 4 waves 2x2, wave tile 96x64.
#define AB1 25600  // A = 200 rows * 128B
__global__ __launch_bounds__(256, 3) void gemm1_kernel(
    const __hip_bfloat16* __restrict__ xT, const __hip_bfloat16* __restrict__ w1t,
    const float* __restrict__ b15, __hip_bfloat16* __restrict__ t1,
    const __hip_bfloat16* __restrict__ zbuf) {
  __shared__ __align__(16) char lds[AB1 + 16384];
  int bid = blockIdx.x;
  bid = (bid & 7) * 96 + (bid >> 3);  // XCD swizzle (768 % 8 == 0)
  const int nb = bid & 1, bh = bid >> 1;
  const int p0 = bh * 192;
  const int tid = threadIdx.x, l = tid & 63, wid = tid >> 6;
  const int wrow = (wid >> 1) * 96, wcol = (wid & 1) * 64;
  const int sboff = (((l & 7) ^ (l >> 3)) << 4);
  const int lrow = l >> 3;
  const int corow0 = nb * 128;

  int b_ad[4][2];
#pragma unroll
  for (int n = 0; n < 4; ++n)
#pragma unroll
    for (int kk = 0; kk < 2; ++kk)
      b_ad[n][kk] = AB1 + (wcol + n * 16 + (l & 15)) * 128 +
                    (((kk * 4 + (l >> 4)) ^ ((l & 15) & 7)) << 4);

  f32x4 acc[6][4] = {};
  const char* xTb = (const char*)xT;
  const char* wB  = (const char*)w1t;
  const char* zb  = (const char*)zbuf;

  for (int cib = 0; cib < 4; ++cib) {
    // stage A halo: rows 0..199 <-> w-coord (row-4); rows outside [4,196) are zero
    for (int is = wid; is < 25; is += 4) {
      int row = is * 8 + lrow;
      const char* src = ((unsigned)(row - 4) < 192u)
          ? xTb + (size_t)(p0 + row - 4) * 512 + cib * 128 + sboff
          : zb + sboff;
      gload_lds16(src, lds + is * 1024);
    }
    for (int k = 0; k < 5; ++k) {
      int boff = k * 512 + cib * 128;
#pragma unroll
      for (int ii = 0; ii < 4; ++ii) {
        int is = wid * 4 + ii;
        const char* bs = wB + (size_t)(corow0 + is * 8 + lrow) * 2560 + boff + sboff;
        gload_lds16(bs, lds + AB1 + is * 1024);
      }
      __syncthreads();
      int x8 = ((l & 15) + k + 2) & 7;
      int arow0 = wrow + (l & 15) + k + 2;
#pragma unroll
      for (int kk = 0; kk < 2; ++kk) {
        int ablk = ((kk * 4 + (l >> 4)) ^ x8) << 4;
        bf16x8 bfr[4];
#pragma unroll
        for (int n = 0; n < 4; ++n) bfr[n] = *(const bf16x8*)(lds + b_ad[n][kk]);
#pragma unroll
        for (int m = 0; m < 6; ++m) {
          bf16x8 af = *(const bf16x8*)(lds + (arow0 + m * 16) * 128 + ablk);
#pragma unroll
          for (int n = 0; n < 4; ++n)
            acc[m][n] = __builtin_amdgcn_mfma_f32_16x16x32_bf16(af, bfr[n], acc[m][n], 0, 0, 0);
        }
      }
      __syncthreads();
    }
  }
#pragma unroll
  for (int n = 0; n < 4; ++n) {
    int co = corow0 + wcol + n * 16 + (l & 15);
    float bias = b15[co];
#pragma unroll
    for (int m = 0; m < 6; ++m) {
      int prow = p0 + wrow + m * 16 + (l >> 4) * 4;
#pragma unroll
      for (int r = 0; r < 4; ++r)
        t1[(size_t)(prow + r) * 256 + co] = __float2bfloat16(acc[m][n][r] + bias);
    }
  }
}

// ---- GEMM2: feat = conv5x1(t1) + conv1x1(xT) + biases -> featT bf16 NHWC.
// Tile = one h-row x 128 co; tap shift is +/-2 h-rows: tile-uniform validity.
#define AB2 24576  // A = 192 rows * 128B
__global__ __launch_bounds__(256, 3) void gemm2_kernel(
    const __hip_bfloat16* __restrict__ t1, const __hip_bfloat16* __restrict__ xT,
    const __hip_bfloat16* __restrict__ w2t,
    const float* __restrict__ b51, const float* __restrict__ b11,
    __hip_bfloat16* __restrict__ featT, const __hip_bfloat16* __restrict__ zbuf) {
  __shared__ __align__(16) char lds[AB2 + 16384];
  int bid = blockIdx.x;
  bid = (bid & 7) * 96 + (bid >> 3);
  const int nb = bid & 1, bh = bid >> 1;
  const int p0 = bh * 192;
  const int h = bh % 192;
  const int tid = threadIdx.x, l = tid & 63, wid = tid >> 6;
  const int wrow = (wid >> 1) * 96, wcol = (wid & 1) * 64;
  const int sboff = (((l & 7) ^ (l >> 3)) << 4);
  const int lrow = l >> 3;
  const int corow0 = nb * 128;

  int a_ad[6][2], b_ad[4][2];
#pragma unroll
  for (int m = 0; m < 6; ++m)
#pragma unroll
    for (int kk = 0; kk < 2; ++kk)
      a_ad[m][kk] = (wrow + m * 16 + (l & 15)) * 128 +
                    (((kk * 4 + (l >> 4)) ^ ((l & 15) & 7)) << 4);
#pragma unroll
  for (int n = 0; n < 4; ++n)
#pragma unroll
    for (int kk = 0; kk < 2; ++kk)
      b_ad[n][kk] = AB2 + (wcol + n * 16 + (l & 15)) * 128 +
                    (((kk * 4 + (l >> 4)) ^ ((l & 15) & 7)) << 4);

  f32x4 acc[6][4] = {};
  const char* t1b = (const char*)t1;
  const char* xTb = (const char*)xT;
  const char* wB  = (const char*)w2t;
  const char* zb  = (const char*)zbuf;

  for (int s = 0; s < 24; ++s) {
    const char* abase;
    int boff;
    if (s < 20) {
      int k = s >> 2, cib = s & 3, dl = k - 2;
      abase = ((unsigned)(h + dl) < 192u)
          ? t1b + (size_t)(p0 + dl * 192) * 512 + cib * 128
          : (const char*)0;
      boff = k * 512 + cib * 128;
    } else {
      abase = xTb + (size_t)p0 * 512 + (s - 20) * 128;
      boff = 2560 + (s - 20) * 128;
    }
    for (int is = wid; is < 24; is += 4) {
      int row = is * 8 + lrow;
      const char* src = abase ? abase + (size_t)row * 512 + sboff : zb + sboff;
      gload_lds16(src, lds + is * 1024);
    }
#pragma unroll
    for (int ii = 0; ii < 4; ++ii) {
      int is = wid * 4 + ii;
      const char* bs = wB + (size_t)(corow0 + is * 8 + lrow) * 3072 + boff + sboff;
      gload_lds16(bs, lds + AB2 + is * 1024);
    }
    __syncthreads();
#pragma unroll
    for (int kk = 0; kk < 2; ++kk) {
      bf16x8 bfr[4];
#pragma unroll
      for (int n = 0; n < 4; ++n) bfr[n] = *(const bf16x8*)(lds + b_ad[n][kk]);
#pragma unroll
      for (int m = 0; m < 6; ++m) {
        bf16x8 af = *(const bf16x8*)(lds + a_ad[m][kk]);
#pragma unroll
        for (int n = 0; n < 4; ++n)
          acc[m][n] = __builtin_amdgcn_mfma_f32_16x16x32_bf16(af, bfr[n], acc[m][n], 0, 0, 0);
      }
    }
    __syncthreads();
  }
#pragma unroll
  for (int n = 0; n < 4; ++n) {
    int co = corow0 + wcol + n * 16 + (l & 15);
    float bias = b51[co] + b11[co];
#pragma unroll
    for (int m = 0; m < 6; ++m) {
      int prow = p0 + wrow + m * 16 + (l >> 4) * 4;
#pragma unroll
      for (int r = 0; r < 4; ++r)
        featT[(size_t)(prow + r) * 256 + co] = __float2bfloat16(acc[m][n][r] + bias);
    }
  }
}

// ---- out = x + feat + bilinear_gather(feat).
// Block = 256 thr / 32 pixels. Phase A: lane=channel, each corner row is ONE
// 512B fully-consumed load; result staged in LDS. Phase B: lane=pixel,
// coalesced NCHW NT stores.
__global__ __launch_bounds__(256) void align_kernel(
    const __hip_bfloat16* __restrict__ xT, const __hip_bfloat16* __restrict__ featT,
    const float* __restrict__ boxes, float* __restrict__ out) {
  __shared__ float vs[32][258];  // [pixel][channel], +2 pad (phase-B 4-way max)
  const int tid = threadIdx.x, l = tid & 63, wv = tid >> 6;
  const int p0 = blockIdx.x * 32;

#pragma unroll 4
  for (int i = 0; i < 8; ++i) {
    int pl = wv * 8 + i;
    int p = p0 + pl;
    int b = p / HW_;
    int p2 = p - b * HW_;
    float yy = boxes[(size_t)p * 5 + 0] * SCALE;
    float xx = boxes[(size_t)p * 5 + 1] * SCALE;
    bool valid = (yy >= -1.0f) && (yy <= (float)H_) && (xx >= -1.0f) && (xx <= (float)W_);
    yy = fmaxf(yy, 0.f);
    xx = fmaxf(xx, 0.f);
    int yl = (int)floorf(yy), xl = (int)floorf(xx);
    int yh, xh;
    if (yl >= H_ - 1) { yl = H_ - 1; yh = H_ - 1; yy = (float)(H_ - 1); } else { yh = yl + 1; }
    if (xl >= W_ - 1) { xl = W_ - 1; xh = W_ - 1; xx = (float)(W_ - 1); } else { xh = xl + 1; }
    float ly = yy - (float)yl, lx = xx - (float)xl;
    float hy = 1.f - ly, hx = 1.f - lx;
    float q00 = hy * hx, q01 = hy * lx, q10 = ly * hx, q11 = ly * lx;
    if (!valid) { q00 = 0.f; q01 = 0.f; q10 = 0.f; q11 = 0.f; }
    const unsigned short* fT = (const unsigned short*)featT + (size_t)b * HW_ * C_;
    const unsigned short* xb = (const unsigned short*)xT + (size_t)b * HW_ * C_;
    int co = l * 4;  // this lane's 4 channels
    uint2 A  = *(const uint2*)(fT + ((size_t)yl * W_ + xl) * C_ + co);
    uint2 Bv = *(const uint2*)(fT + ((size_t)yl * W_ + xh) * C_ + co);
    uint2 Cv = *(const uint2*)(fT + ((size_t)yh * W_ + xl) * C_ + co);
    uint2 D  = *(const uint2*)(fT + ((size_t)yh * W_ + xh) * C_ + co);
    uint2 E  = *(const uint2*)(fT + (size_t)p2 * C_ + co);
    uint2 X  = *(const uint2*)(xb + (size_t)p2 * C_ + co);
    float o[4];
#pragma unroll
    for (int w = 0; w < 2; ++w) {
      unsigned int aw = (&A.x)[w], bw = (&Bv.x)[w], cw = (&Cv.x)[w],
                   dw = (&D.x)[w], ew = (&E.x)[w], xw = (&X.x)[w];
      float a0 = __uint_as_float(aw << 16), a1 = __uint_as_float(aw & 0xffff0000u);
      float b0 = __uint_as_float(bw << 16), b1 = __uint_as_float(bw & 0xffff0000u);
      float c0 = __uint_as_float(cw << 16), c1 = __uint_as_float(cw & 0xffff0000u);
      float d0 = __uint_as_float(dw << 16), d1 = __uint_as_float(dw & 0xffff0000u);
      float e0 = __uint_as_float(ew << 16), e1 = __uint_as_float(ew & 0xffff0000u);
      float x0 = __uint_as_float(xw << 16), x1 = __uint_as_float(xw & 0xffff0000u);
      o[w * 2 + 0] = x0 + e0 + q00 * a0 + q01 * b0 + q10 * c0 + q11 * d0;
      o[w * 2 + 1] = x1 + e1 + q00 * a1 + q01 * b1 + q10 * c1 + q11 * d1;
    }
    *(float2*)&vs[pl][co]     = make_float2(o[0], o[1]);
    *(float2*)&vs[pl][co + 2] = make_float2(o[2], o[3]);
  }
  __syncthreads();

  // Phase B: lane=pixel, coalesced NCHW writes
  const int pl = tid & 31, cg = tid >> 5;
  const int p = p0 + pl;
  const int b = p / HW_;
  const int p2 = p - b * HW_;
  float* oc = out + (size_t)b * CHW_ + p2;
#pragma unroll
  for (int j = 0; j < 32; ++j) {
    int ch = cg * 32 + j;
    __builtin_nontemporal_store(vs[pl][ch], &oc[(size_t)ch * HW_]);
  }
}

extern "C" void kernel_launch(void* const* d_in, const int* in_sizes, int n_in,
                              void* d_out, int out_size, void* d_ws, size_t ws_size,
                              hipStream_t stream) {
  const float* x     = (const float*)d_in[0];
  const float* boxes = (const float*)d_in[1];
  const float* w51   = (const float*)d_in[2];
  const float* b51   = (const float*)d_in[3];
  const float* w15   = (const float*)d_in[4];
  const float* b15   = (const float*)d_in[5];
  const float* w11   = (const float*)d_in[6];
  const float* b11   = (const float*)d_in[7];
  float* out = (float*)d_out;

  // d_ws: featT bf16 NHWC | xT bf16 NHWC | w1t | w2t | zbuf  (~77 MB)
  __hip_bfloat16* featT = (__hip_bfloat16*)d_ws;
  __hip_bfloat16* xT   = featT + (size_t)P_ * C_;
  __hip_bfloat16* w1t  = xT + (size_t)P_ * C_;
  __hip_bfloat16* w2t  = w1t + (size_t)C_ * 1280;
  __hip_bfloat16* zbuf = w2t + (size_t)C_ * 1536;
  // d_out doubles as scratch for t1 (dead before align writes out)
  __hip_bfloat16* t1 = (__hip_bfloat16*)d_out;

  wtrans_kernel<<<dim3((C_ * C_ * 5 + 255) / 256), 256, 0, stream>>>(
      w15, w51, w11, w1t, w2t, zbuf);
  nchw2nhwc_kernel<<<dim3(HW_ / 32, C_ / 32, B_), dim3(32, 8), 0, stream>>>(x, xT);
  gemm1_kernel<<<dim3(768), 256, 0, stream>>>(xT, w1t, b15, t1, zbuf);
  gemm2_kernel<<<dim3(768), 256, 0, stream>>>(t1, xT, w2t, b51, b11, featT, zbuf);
  align_kernel<<<dim3(P_ / 32), 256, 0, stream>>>(xT, featT, boxes, out);
}

// Round 7
// 172.575 us; speedup vs baseline: 10.6693x; 1.0034x over previous
//
#include <hip/hip_runtime.h>
#include <hip/hip_bf16.h>
#include <stdint.h>

#define B_ 2
#define C_ 256
#define H_ 192
#define W_ 192
#define HW_ (H_*W_)
#define CHW_ (C_*HW_)
#define P_ (B_*HW_)
#define SCALE 0.125f

typedef __attribute__((ext_vector_type(8))) short bf16x8;
typedef __attribute__((ext_vector_type(4))) float f32x4;

__device__ __forceinline__ void gload_lds16(const void* g, void* l) {
  __builtin_amdgcn_global_load_lds(
      (const __attribute__((address_space(1))) uint32_t*)g,
      (__attribute__((address_space(3))) uint32_t*)l, 16, 0, 0);
}

// ---- weights: w15/w51 [co][ci][k] fp32 -> bf16 [co][k*256+ci]; w11 appended; zero zbuf
__global__ __launch_bounds__(256) void wtrans_kernel(
    const float* __restrict__ w15, const float* __restrict__ w51,
    const float* __restrict__ w11,
    __hip_bfloat16* __restrict__ w1t, __hip_bfloat16* __restrict__ w2t,
    __hip_bfloat16* __restrict__ zbuf) {
  int i = blockIdx.x * 256 + threadIdx.x;
  if (i < C_ * C_ * 5) {
    int co = i / (C_ * 5);
    int r  = i - co * (C_ * 5);
    int ci = r / 5;
    int k  = r - ci * 5;
    w1t[(size_t)co * 1280 + k * 256 + ci] = __float2bfloat16(w15[i]);
    w2t[(size_t)co * 1536 + k * 256 + ci] = __float2bfloat16(w51[i]);
  }
  if (i < C_ * C_) {
    int co = i >> 8, ci = i & 255;
    w2t[(size_t)co * 1536 + 1280 + ci] = __float2bfloat16(w11[i]);
  }
  if (i < 1024) zbuf[i] = __float2bfloat16(0.f);
}

// ---- x NCHW fp32 -> xT NHWC bf16 (LDS 32x32 tile transpose)
__global__ __launch_bounds__(256) void nchw2nhwc_kernel(
    const float* __restrict__ x, __hip_bfloat16* __restrict__ xT) {
  __shared__ float tile[32][33];
  int p0 = blockIdx.x * 32, c0 = blockIdx.y * 32, b = blockIdx.z;
  int tx = threadIdx.x, ty = threadIdx.y;
  const float* xb = x + (size_t)b * CHW_;
#pragma unroll
  for (int j = 0; j < 4; ++j)
    tile[ty + j * 8][tx] = xb[(size_t)(c0 + ty + j * 8) * HW_ + p0 + tx];
  __syncthreads();
  __hip_bfloat16* xo = xT + (size_t)b * HW_ * C_;
#pragma unroll
  for (int j = 0; j < 4; ++j)
    xo[(size_t)(p0 + ty + j * 8) * C_ + c0 + tx] = __float2bfloat16(tile[tx][ty + j * 8]);
}

// ---- GEMM1 (frozen): t1[p][co] = bf16(conv1x5(xT)+b15). Tile = one h-row x 128 co.
#define AB1 25600  // A = 200 rows * 128B
__global__ __launch_bounds__(256, 3) void gemm1_kernel(
    const __hip_bfloat16* __restrict__ xT, const __hip_bfloat16* __restrict__ w1t,
    const float* __restrict__ b15, __hip_bfloat16* __restrict__ t1,
    const __hip_bfloat16* __restrict__ zbuf) {
  __shared__ __align__(16) char lds[AB1 + 16384];
  int bid = blockIdx.x;
  bid = (bid & 7) * 96 + (bid >> 3);  // XCD swizzle (768 % 8 == 0)
  const int nb = bid & 1, bh = bid >> 1;
  const int p0 = bh * 192;
  const int tid = threadIdx.x, l = tid & 63, wid = tid >> 6;
  const int wrow = (wid >> 1) * 96, wcol = (wid & 1) * 64;
  const int sboff = (((l & 7) ^ (l >> 3)) << 4);
  const int lrow = l >> 3;
  const int corow0 = nb * 128;

  int b_ad[4][2];
#pragma unroll
  for (int n = 0; n < 4; ++n)
#pragma unroll
    for (int kk = 0; kk < 2; ++kk)
      b_ad[n][kk] = AB1 + (wcol + n * 16 + (l & 15)) * 128 +
                    (((kk * 4 + (l >> 4)) ^ ((l & 15) & 7)) << 4);

  f32x4 acc[6][4] = {};
  const char* xTb = (const char*)xT;
  const char* wB  = (const char*)w1t;
  const char* zb  = (const char*)zbuf;

  for (int cib = 0; cib < 4; ++cib) {
    for (int is = wid; is < 25; is += 4) {
      int row = is * 8 + lrow;
      const char* src = ((unsigned)(row - 4) < 192u)
          ? xTb + (size_t)(p0 + row - 4) * 512 + cib * 128 + sboff
          : zb + sboff;
      gload_lds16(src, lds + is * 1024);
    }
    for (int k = 0; k < 5; ++k) {
      int boff = k * 512 + cib * 128;
#pragma unroll
      for (int ii = 0; ii < 4; ++ii) {
        int is = wid * 4 + ii;
        const char* bs = wB + (size_t)(corow0 + is * 8 + lrow) * 2560 + boff + sboff;
        gload_lds16(bs, lds + AB1 + is * 1024);
      }
      __syncthreads();
      int x8 = ((l & 15) + k + 2) & 7;
      int arow0 = wrow + (l & 15) + k + 2;
#pragma unroll
      for (int kk = 0; kk < 2; ++kk) {
        int ablk = ((kk * 4 + (l >> 4)) ^ x8) << 4;
        bf16x8 bfr[4];
#pragma unroll
        for (int n = 0; n < 4; ++n) bfr[n] = *(const bf16x8*)(lds + b_ad[n][kk]);
#pragma unroll
        for (int m = 0; m < 6; ++m) {
          bf16x8 af = *(const bf16x8*)(lds + (arow0 + m * 16) * 128 + ablk);
#pragma unroll
          for (int n = 0; n < 4; ++n)
            acc[m][n] = __builtin_amdgcn_mfma_f32_16x16x32_bf16(af, bfr[n], acc[m][n], 0, 0, 0);
        }
      }
      __syncthreads();
    }
  }
#pragma unroll
  for (int n = 0; n < 4; ++n) {
    int co = corow0 + wcol + n * 16 + (l & 15);
    float bias = b15[co];
#pragma unroll
    for (int m = 0; m < 6; ++m) {
      int prow = p0 + wrow + m * 16 + (l >> 4) * 4;
#pragma unroll
      for (int r = 0; r < 4; ++r)
        t1[(size_t)(prow + r) * 256 + co] = __float2bfloat16(acc[m][n][r] + bias);
    }
  }
}

// ---- GEMM2 (NEW): pipelined dbuf + counted vmcnt + raw barriers + setprio.
// BM=192 (one h-row) x BN=128, BK=64, 512 thr (8 waves, wave tile 48x64).
// LDS: A dbuf 2x24K @0, B dbuf 2x16K @48K = 80 KB -> 2 blocks/CU.
#define A2SZ 24576
#define B2OFF 49152
__global__ __launch_bounds__(512, 4) void gemm2_kernel(
    const __hip_bfloat16* __restrict__ t1, const __hip_bfloat16* __restrict__ xT,
    const __hip_bfloat16* __restrict__ w2t,
    const float* __restrict__ b51, const float* __restrict__ b11,
    __hip_bfloat16* __restrict__ featT, const __hip_bfloat16* __restrict__ zbuf) {
  __shared__ __align__(16) char lds[81920];
  int bid = blockIdx.x;
  bid = (bid & 7) * 96 + (bid >> 3);  // XCD swizzle (768 % 8 == 0)
  const int nb = bid & 1, bh = bid >> 1;
  const int p0 = bh * 192;
  const int h = bh % 192;
  const int tid = threadIdx.x, l = tid & 63, wid = tid >> 6;
  const int wrow = (wid >> 1) * 48, wcol = (wid & 1) * 64;
  const int sboff = (((l & 7) ^ (l >> 3)) << 4);
  const int lrow = l >> 3;
  const int corow0 = nb * 128;

  const char* t1b = (const char*)t1;
  const char* xTb = (const char*)xT;
  const char* wB  = (const char*)w2t;
  const char* zb  = (const char*)zbuf;

  // 3 uniform 16B loads/thread: A tile 192rows x 128B into buf (24 slots x 1KB)
  auto stageA = [&](int s, int buf) {
    const char* abase;
    if (s < 20) {
      int k = s >> 2, cib = s & 3, dl = k - 2;
      abase = ((unsigned)(h + dl) < 192u)
          ? t1b + (size_t)(p0 + dl * 192) * 512 + cib * 128
          : (const char*)0;
    } else {
      abase = xTb + (size_t)p0 * 512 + (s - 20) * 128;
    }
#pragma unroll
    for (int i = 0; i < 3; ++i) {
      int slot = i * 8 + wid;
      int row = slot * 8 + lrow;
      const char* src = abase ? abase + (size_t)row * 512 + sboff : zb + sboff;
      gload_lds16(src, lds + buf * A2SZ + slot * 1024);
    }
  };
  // 2 uniform loads/thread: B tile 128co x 128B (16 slots x 1KB)
  auto stageB = [&](int s, int buf) {
    int boff = (s < 20) ? (s >> 2) * 512 + (s & 3) * 128 : 2560 + (s - 20) * 128;
#pragma unroll
    for (int i = 0; i < 2; ++i) {
      int slot = i * 8 + wid;
      const char* bs = wB + (size_t)(corow0 + slot * 8 + lrow) * 3072 + boff + sboff;
      gload_lds16(bs, lds + B2OFF + buf * 16384 + slot * 1024);
    }
  };

  f32x4 acc[3][4] = {};
  stageA(0, 0);
  stageB(0, 0);
  for (int t = 0; t < 24; ++t) {
    const int cur = t & 1, nxt = cur ^ 1;
    if (t < 23) {
      stageA(t + 1, nxt);  // 3 loads in flight across this whole iteration
      asm volatile("s_waitcnt vmcnt(3)" ::: "memory");  // tile t's 5 done
    } else {
      asm volatile("s_waitcnt vmcnt(0)" ::: "memory");
    }
    __builtin_amdgcn_s_barrier();          // all waves: buf[cur] ready
    __builtin_amdgcn_sched_barrier(0);
    const char* la = lds + cur * A2SZ;
    const char* lb = lds + B2OFF + cur * 16384;
    // phase kk=0
    {
      bf16x8 af[3], bfr[4];
#pragma unroll
      for (int m = 0; m < 3; ++m)
        af[m] = *(const bf16x8*)(la + (wrow + m * 16 + (l & 15)) * 128 +
                 (((l >> 4) ^ ((l & 15) & 7)) << 4));
#pragma unroll
      for (int n = 0; n < 4; ++n)
        bfr[n] = *(const bf16x8*)(lb + (wcol + n * 16 + (l & 15)) * 128 +
                 (((l >> 4) ^ ((l & 15) & 7)) << 4));
      __builtin_amdgcn_s_setprio(1);
#pragma unroll
      for (int m = 0; m < 3; ++m)
#pragma unroll
        for (int n = 0; n < 4; ++n)
          acc[m][n] = __builtin_amdgcn_mfma_f32_16x16x32_bf16(af[m], bfr[n], acc[m][n], 0, 0, 0);
      __builtin_amdgcn_s_setprio(0);
    }
    if (t < 23) stageB(t + 1, nxt);  // 2 more loads for tile t+1
    // phase kk=1
    {
      bf16x8 af[3], bfr[4];
#pragma unroll
      for (int m = 0; m < 3; ++m)
        af[m] = *(const bf16x8*)(la + (wrow + m * 16 + (l & 15)) * 128 +
                 (((4 + (l >> 4)) ^ ((l & 15) & 7)) << 4));
#pragma unroll
      for (int n = 0; n < 4; ++n)
        bfr[n] = *(const bf16x8*)(lb + (wcol + n * 16 + (l & 15)) * 128 +
                 (((4 + (l >> 4)) ^ ((l & 15) & 7)) << 4));
      __builtin_amdgcn_s_setprio(1);
#pragma unroll
      for (int m = 0; m < 3; ++m)
#pragma unroll
        for (int n = 0; n < 4; ++n)
          acc[m][n] = __builtin_amdgcn_mfma_f32_16x16x32_bf16(af[m], bfr[n], acc[m][n], 0, 0, 0);
      __builtin_amdgcn_s_setprio(0);
    }
    __builtin_amdgcn_sched_barrier(0);
    __builtin_amdgcn_s_barrier();          // all waves done reading buf[cur]
    __builtin_amdgcn_sched_barrier(0);
  }
#pragma unroll
  for (int n = 0; n < 4; ++n) {
    int co = corow0 + wcol + n * 16 + (l & 15);
    float bias = b51[co] + b11[co];
#pragma unroll
    for (int m = 0; m < 3; ++m) {
      int prow = p0 + wrow + m * 16 + (l >> 4) * 4;
#pragma unroll
      for (int r = 0; r < 4; ++r)
        featT[(size_t)(prow + r) * 256 + co] = __float2bfloat16(acc[m][n][r] + bias);
    }
  }
}

// ---- out = x + feat + bilinear_gather(feat)  (frozen)
__global__ __launch_bounds__(256) void align_kernel(
    const __hip_bfloat16* __restrict__ xT, const __hip_bfloat16* __restrict__ featT,
    const float* __restrict__ boxes, float* __restrict__ out) {
  __shared__ float vs[32][258];
  const int tid = threadIdx.x, l = tid & 63, wv = tid >> 6;
  const int p0 = blockIdx.x * 32;

#pragma unroll 4
  for (int i = 0; i < 8; ++i) {
    int pl = wv * 8 + i;
    int p = p0 + pl;
    int b = p / HW_;
    int p2 = p - b * HW_;
    float yy = boxes[(size_t)p * 5 + 0] * SCALE;
    float xx = boxes[(size_t)p * 5 + 1] * SCALE;
    bool valid = (yy >= -1.0f) && (yy <= (float)H_) && (xx >= -1.0f) && (xx <= (float)W_);
    yy = fmaxf(yy, 0.f);
    xx = fmaxf(xx, 0.f);
    int yl = (int)floorf(yy), xl = (int)floorf(xx);
    int yh, xh;
    if (yl >= H_ - 1) { yl = H_ - 1; yh = H_ - 1; yy = (float)(H_ - 1); } else { yh = yl + 1; }
    if (xl >= W_ - 1) { xl = W_ - 1; xh = W_ - 1; xx = (float)(W_ - 1); } else { xh = xl + 1; }
    float ly = yy - (float)yl, lx = xx - (float)xl;
    float hy = 1.f - ly, hx = 1.f - lx;
    float q00 = hy * hx, q01 = hy * lx, q10 = ly * hx, q11 = ly * lx;
    if (!valid) { q00 = 0.f; q01 = 0.f; q10 = 0.f; q11 = 0.f; }
    const unsigned short* fT = (const unsigned short*)featT + (size_t)b * HW_ * C_;
    const unsigned short* xb = (const unsigned short*)xT + (size_t)b * HW_ * C_;
    int co = l * 4;
    uint2 A  = *(const uint2*)(fT + ((size_t)yl * W_ + xl) * C_ + co);
    uint2 Bv = *(const uint2*)(fT + ((size_t)yl * W_ + xh) * C_ + co);
    uint2 Cv = *(const uint2*)(fT + ((size_t)yh * W_ + xl) * C_ + co);
    uint2 D  = *(const uint2*)(fT + ((size_t)yh * W_ + xh) * C_ + co);
    uint2 E  = *(const uint2*)(fT + (size_t)p2 * C_ + co);
    uint2 X  = *(const uint2*)(xb + (size_t)p2 * C_ + co);
    float o[4];
#pragma unroll
    for (int w = 0; w < 2; ++w) {
      unsigned int aw = (&A.x)[w], bw = (&Bv.x)[w], cw = (&Cv.x)[w],
                   dw = (&D.x)[w], ew = (&E.x)[w], xw = (&X.x)[w];
      float a0 = __uint_as_float(aw << 16), a1 = __uint_as_float(aw & 0xffff0000u);
      float b0 = __uint_as_float(bw << 16), b1 = __uint_as_float(bw & 0xffff0000u);
      float c0 = __uint_as_float(cw << 16), c1 = __uint_as_float(cw & 0xffff0000u);
      float d0 = __uint_as_float(dw << 16), d1 = __uint_as_float(dw & 0xffff0000u);
      float e0 = __uint_as_float(ew << 16), e1 = __uint_as_float(ew & 0xffff0000u);
      float x0 = __uint_as_float(xw << 16), x1 = __uint_as_float(xw & 0xffff0000u);
      o[w * 2 + 0] = x0 + e0 + q00 * a0 + q01 * b0 + q10 * c0 + q11 * d0;
      o[w * 2 + 1] = x1 + e1 + q00 * a1 + q01 * b1 + q10 * c1 + q11 * d1;
    }
    *(float2*)&vs[pl][co]     = make_float2(o[0], o[1]);
    *(float2*)&vs[pl][co + 2] = make_float2(o[2], o[3]);
  }
  __syncthreads();

  const int pl = tid & 31, cg = tid >> 5;
  const int p = p0 + pl;
  const int b = p / HW_;
  const int p2 = p - b * HW_;
  float* oc = out + (size_t)b * CHW_ + p2;
#pragma unroll
  for (int j = 0; j < 32; ++j) {
    int ch = cg * 32 + j;
    __builtin_nontemporal_store(vs[pl][ch], &oc[(size_t)ch * HW_]);
  }
}

extern "C" void kernel_launch(void* const* d_in, const int* in_sizes, int n_in,
                              void* d_out, int out_size, void* d_ws, size_t ws_size,
                              hipStream_t stream) {
  const float* x     = (const float*)d_in[0];
  const float* boxes = (const float*)d_in[1];
  const float* w51   = (const float*)d_in[2];
  const float* b51   = (const float*)d_in[3];
  const float* w15   = (const float*)d_in[4];
  const float* b15   = (const float*)d_in[5];
  const float* w11   = (const float*)d_in[6];
  const float* b11   = (const float*)d_in[7];
  float* out = (float*)d_out;

  __hip_bfloat16* featT = (__hip_bfloat16*)d_ws;
  __hip_bfloat16* xT   = featT + (size_t)P_ * C_;
  __hip_bfloat16* w1t  = xT + (size_t)P_ * C_;
  __hip_bfloat16* w2t  = w1t + (size_t)C_ * 1280;
  __hip_bfloat16* zbuf = w2t + (size_t)C_ * 1536;
  __hip_bfloat16* t1 = (__hip_bfloat16*)d_out;

  wtrans_kernel<<<dim3((C_ * C_ * 5 + 255) / 256), 256, 0, stream>>>(
      w15, w51, w11, w1t, w2t, zbuf);
  nchw2nhwc_kernel<<<dim3(HW_ / 32, C_ / 32, B_), dim3(32, 8), 0, stream>>>(x, xT);
  gemm1_kernel<<<dim3(768), 256, 0, stream>>>(xT, w1t, b15, t1, zbuf);
  gemm2_kernel<<<dim3(768), 512, 0, stream>>>(t1, xT, w2t, b51, b11, featT, zbuf);
  align_kernel<<<dim3(P_ / 32), 256, 0, stream>>>(xT, featT, boxes, out);
}